// Round 4
// baseline (1000.578 us; speedup 1.0000x reference)
//
#include <hip/hip_runtime.h>
#include <stdint.h>

#define H     1024
#define K2    2048
#define NTOT  5120
#define BATCH 64
#define BM 128
#define BN 128
#define BK 64

typedef unsigned short u16;
typedef __attribute__((ext_vector_type(8))) short short8;
typedef __attribute__((ext_vector_type(4))) float floatx4;

__device__ __forceinline__ float bf2f(u16 u) {
    return __uint_as_float(((uint32_t)u) << 16);
}
__device__ __forceinline__ u16 f2bf(float f) {
    uint32_t u = __float_as_uint(f);
    u += 0x7fffu + ((u >> 16) & 1u);
    return (u16)(u >> 16);
}
__device__ __forceinline__ uint32_t pk2(float lo, float hi) {
    return (uint32_t)f2bf(lo) | ((uint32_t)f2bf(hi) << 16);
}
__device__ __forceinline__ float sigf(float x) {
    return 1.0f / (1.0f + __expf(-x));
}
__device__ __forceinline__ float tanh_(float x) {
    float e = __expf(-2.0f * fabsf(x));
    float r = (1.0f - e) / (1.0f + e);
    return copysignf(r, x);
}

// ---- pack weights (fp32 in) -> bf16 WT[n][k]; k<1024 from W, else U ----
__global__ void pack_weights(const float* __restrict__ Wio, const float* __restrict__ Uio,
                             const float* __restrict__ Wfl, const float* __restrict__ Ufl,
                             const float* __restrict__ Wfr, const float* __restrict__ Ufr,
                             u16* __restrict__ WT) {
    __shared__ u16 tile[32][33];
    int k0 = blockIdx.x * 32;
    int n0 = blockIdx.y * 32;
    const float *Wp, *Up; int ncols, nloc;
    if (n0 < 3072)      { Wp = Wio; Up = Uio; ncols = 3072; nloc = n0; }
    else if (n0 < 4096) { Wp = Wfl; Up = Ufl; ncols = 1024; nloc = n0 - 3072; }
    else                { Wp = Wfr; Up = Ufr; ncols = 1024; nloc = n0 - 4096; }
    int t = threadIdx.x;
    int c = t & 31, r = t >> 5;
#pragma unroll
    for (int i = 0; i < 4; ++i) {
        int rr = r + i * 8;
        int k = k0 + rr;
        float v = (k < 1024) ? Wp[(long)k * ncols + nloc + c]
                             : Up[(long)(k - 1024) * ncols + nloc + c];
        tile[rr][c] = f2bf(v);
    }
    __syncthreads();
#pragma unroll
    for (int i = 0; i < 4; ++i) {
        int rr = r + i * 8;
        WT[(long)(n0 + rr) * K2 + k0 + c] = tile[c][rr];
    }
}

// ---- leaf gather + fp32->bf16: leaf[node][d] = emb[tokens[node]][d] ----
__global__ void leaf_pack(const int* __restrict__ tokens, const float* __restrict__ emb,
                          u16* __restrict__ leaf) {
    int idx = blockIdx.x * 256 + threadIdx.x;   // 16384 blocks -> 4,194,304 float4
    int node = idx >> 8;
    int d4 = idx & 255;
    int tok = tokens[node];
    float4 v = ((const float4*)emb)[(long)tok * 256 + d4];
    uint2 o; o.x = pk2(v.x, v.y); o.y = pk2(v.z, v.w);
    ((uint2*)leaf)[(long)node * 256 + d4] = o;
}

// ---- GEMM (m97 structure, 128x128) for small row counts ----
__global__ void gemm_bt(const u16* __restrict__ A, const u16* __restrict__ BT,
                        float* __restrict__ G, int mc) {
    __shared__ __align__(16) u16 AsBs[16896];   // 33,792 B; K-loop: As|Bs, epilogue: epi
    u16* As = AsBs;
    u16* Bs = AsBs + 8192;
    float* epi = (float*)AsBs;                  // 64 x 132 fp32
    int tid  = threadIdx.x;
    int lane = tid & 63;
    int w    = tid >> 6;
    int wm   = w >> 1, wn = w & 1;
    int rowTile = blockIdx.x * BM;
    int n0      = blockIdx.y * BN;

    const u16* asrc[4];
    const u16* bsrc[4];
#pragma unroll
    for (int cc = 0; cc < 4; ++cc) {
        int r = cc * 32 + w * 8 + (lane >> 3);
        int j = rowTile + r; if (j >= mc) j = mc - 1;
        asrc[cc] = A + (long)j * K2 + (lane & 7) * 8;
        bsrc[cc] = BT + (long)(n0 + r) * K2 + (lane & 7) * 8;
    }

    floatx4 acc[4][4];
#pragma unroll
    for (int mt = 0; mt < 4; ++mt)
#pragma unroll
        for (int nt = 0; nt < 4; ++nt)
            acc[mt][nt] = (floatx4){0.f, 0.f, 0.f, 0.f};

    for (int k0 = 0; k0 < K2; k0 += BK) {
#pragma unroll
        for (int cc = 0; cc < 4; ++cc) {
            __builtin_amdgcn_global_load_lds(
                (const __attribute__((address_space(1))) void*)(asrc[cc] + k0),
                (__attribute__((address_space(3))) void*)(As + cc * 2048 + w * 512), 16, 0, 0);
            __builtin_amdgcn_global_load_lds(
                (const __attribute__((address_space(1))) void*)(bsrc[cc] + k0),
                (__attribute__((address_space(3))) void*)(Bs + cc * 2048 + w * 512), 16, 0, 0);
        }
        __syncthreads();
#pragma unroll
        for (int kb = 0; kb < 2; ++kb) {
            int kfo = kb * 32 + (lane >> 4) * 8;
            short8 af[4], bfv[4];
#pragma unroll
            for (int mt = 0; mt < 4; ++mt)
                af[mt] = *(const short8*)&As[(wm * 64 + mt * 16 + (lane & 15)) * BK + kfo];
#pragma unroll
            for (int nt = 0; nt < 4; ++nt)
                bfv[nt] = *(const short8*)&Bs[(wn * 64 + nt * 16 + (lane & 15)) * BK + kfo];
#pragma unroll
            for (int mt = 0; mt < 4; ++mt)
#pragma unroll
                for (int nt = 0; nt < 4; ++nt)
                    acc[mt][nt] = __builtin_amdgcn_mfma_f32_16x16x32_bf16(
                        af[mt], bfv[nt], acc[mt][nt], 0, 0, 0);
        }
        __syncthreads();
    }

    // ---- epilogue: LDS round-trip -> fully coalesced float4 stores ----
#pragma unroll
    for (int s = 0; s < 2; ++s) {
        if (wm == s) {
#pragma unroll
            for (int mt = 0; mt < 4; ++mt)
#pragma unroll
                for (int r = 0; r < 4; ++r) {
                    int lrow = mt * 16 + (lane >> 4) * 4 + r;
#pragma unroll
                    for (int nt = 0; nt < 4; ++nt)
                        epi[lrow * 132 + wn * 64 + nt * 16 + (lane & 15)] = acc[mt][nt][r];
                }
        }
        __syncthreads();
        int gr0 = rowTile + s * 64;
#pragma unroll
        for (int k = 0; k < 8; ++k) {
            int f4 = tid + k * 256;     // 0..2047 float4 slots = 64 rows x 32
            int row = f4 >> 5, c4 = f4 & 31;
            if (gr0 + row < mc) {
                float4 v = *(const float4*)&epi[row * 132 + c4 * 4];
                *(float4*)&G[(long)(gr0 + row) * NTOT + n0 + c4 * 4] = v;
            }
        }
        __syncthreads();
    }
}

// ==== 256x256 8-phase pipelined GEMM, fragment-granule LDS (conflict-free) ===
// 512 threads = 8 waves. Wave (wm=w>>2, wn=w&3) owns C rows {wm*64..+63} u
// {128+wm*64..+63}, cols {wn*32..+31} u {128+wn*32..+31}.
// LDS: 2 dbuf x 4 slots [A0|A1|B0|B1], 16KB each. Slot layout = fragment
// granules: [ks:2][rowblock:8][kq:4][row:16] x 16B. A wave's MFMA fragment
// (rb,ks) is the 1KB run at slot + ks*8192 + rb*1024, lane l at +l*16 ->
// ds_read_b128 is 1024 CONTIGUOUS bytes per wave = zero bank conflicts.
// Stage call (slot, rg=ks): linear LDS dest (tid*16B); global src decodes the
// granule: wave w stages rowblock w, lane -> (kq=lane>>4, row=lane&15); per
// row the 4 kq lanes are 64B contiguous -> 16 cache lines/instr (no waste).
// Schedule per tile t (dbuf d=t&1), 4 phases (quadrants), 16 MFMA each.
// FIFO (per wave, 2 loads/stage): entering P0 queue=[A0,B0,B1,A1]x2=8.
// P0: vmcnt(4) drains A0,B0 (read here); stage A0' -> 6.
// P1: vmcnt(4) drains B1 (read here);   stage B0' -> 6.
// P2: vmcnt(4) drains A1 (read here);   stage B1' -> 6.
// P3: no wait;                          stage A1' -> 8.  Last tile: 4/2/0.
#define GP_STAGE(T1, DD, SLOT)                                                       \
    do {                                                                             \
        _Pragma("unroll")                                                            \
        for (int rg = 0; rg < 2; ++rg)                                               \
            __builtin_amdgcn_global_load_lds(                                        \
                (const __attribute__((address_space(1))) void*)(srcS[SLOT] + rg * 32 + (T1) * 64), \
                (__attribute__((address_space(3))) void*)(lds + (DD) * 32768 + (SLOT) * 8192 + rg * 4096 + tid * 8), \
                16, 0, 0);                                                           \
    } while (0)

#define GP_MFMA(MB, NB, AF, BF)                                                      \
    do {                                                                             \
        __builtin_amdgcn_s_setprio(1);                                               \
        _Pragma("unroll")                                                            \
        for (int ks = 0; ks < 2; ++ks)                                               \
            _Pragma("unroll")                                                        \
            for (int m2 = 0; m2 < 4; ++m2)                                           \
                _Pragma("unroll")                                                    \
                for (int n2 = 0; n2 < 2; ++n2)                                       \
                    acc[(MB) + m2][(NB) + n2] = __builtin_amdgcn_mfma_f32_16x16x32_bf16( \
                        AF[ks][m2], BF[ks][n2], acc[(MB) + m2][(NB) + n2], 0, 0, 0); \
        __builtin_amdgcn_s_setprio(0);                                               \
    } while (0)

#define GP_TILE(T, D, LASTQ)                                                         \
    do {                                                                             \
        const u16* ldsD = lds + (D) * 32768;                                         \
        /* ---- P0: quadrant (0,0) ---- */                                           \
        asm volatile("s_waitcnt vmcnt(4)" ::: "memory");                             \
        asm volatile("s_barrier" ::: "memory");                                      \
        _Pragma("unroll")                                                            \
        for (int ks = 0; ks < 2; ++ks) {                                             \
            _Pragma("unroll")                                                        \
            for (int m2 = 0; m2 < 4; ++m2)                                           \
                aF[ks][m2] = *(const short8*)&ldsD[aOffP[m2] + ks * 4096];           \
            _Pragma("unroll")                                                        \
            for (int n2 = 0; n2 < 2; ++n2)                                           \
                b0F[ks][n2] = *(const short8*)&ldsD[bOffP[n2] + ks * 4096];          \
        }                                                                            \
        if (!(LASTQ)) GP_STAGE((T) + 1, (D) ^ 1, 0);                                 \
        GP_MFMA(0, 0, aF, b0F);                                                      \
        asm volatile("s_barrier" ::: "memory");                                      \
        /* ---- P1: quadrant (0,1) ---- */                                           \
        if (!(LASTQ)) asm volatile("s_waitcnt vmcnt(4)" ::: "memory");               \
        else          asm volatile("s_waitcnt vmcnt(2)" ::: "memory");               \
        asm volatile("s_barrier" ::: "memory");                                      \
        _Pragma("unroll")                                                            \
        for (int ks = 0; ks < 2; ++ks)                                               \
            _Pragma("unroll")                                                        \
            for (int n2 = 0; n2 < 2; ++n2)                                           \
                b1F[ks][n2] = *(const short8*)&ldsD[bOffP[2 + n2] + ks * 4096];      \
        if (!(LASTQ)) GP_STAGE((T) + 1, (D) ^ 1, 2);                                 \
        GP_MFMA(0, 2, aF, b1F);                                                      \
        asm volatile("s_barrier" ::: "memory");                                      \
        /* ---- P2: quadrant (1,0) ---- */                                           \
        if (!(LASTQ)) asm volatile("s_waitcnt vmcnt(4)" ::: "memory");               \
        else          asm volatile("s_waitcnt vmcnt(0)" ::: "memory");               \
        asm volatile("s_barrier" ::: "memory");                                      \
        _Pragma("unroll")                                                            \
        for (int ks = 0; ks < 2; ++ks)                                               \
            _Pragma("unroll")                                                        \
            for (int m2 = 0; m2 < 4; ++m2)                                           \
                aF[ks][m2] = *(const short8*)&ldsD[aOffP[4 + m2] + ks * 4096];       \
        if (!(LASTQ)) GP_STAGE((T) + 1, (D) ^ 1, 3);                                 \
        GP_MFMA(4, 0, aF, b0F);                                                      \
        asm volatile("s_barrier" ::: "memory");                                      \
        /* ---- P3: quadrant (1,1) ---- */                                           \
        if (!(LASTQ)) GP_STAGE((T) + 1, (D) ^ 1, 1);                                 \
        GP_MFMA(4, 2, aF, b1F);                                                      \
        asm volatile("s_barrier" ::: "memory");                                      \
    } while (0)

__global__ __launch_bounds__(512, 2) void gemmP(const u16* __restrict__ A,
                                                const u16* __restrict__ BT,
                                                float* __restrict__ G, int gm) {
    __shared__ __align__(16) u16 lds[65536];    // 128 KiB -> 1 block/CU
    const int tid  = threadIdx.x;
    const int lane = tid & 63;
    const int w    = tid >> 6;
    const int wm   = w >> 2, wn = w & 3;

    // XCD-bijective swizzle (m204); n-tile fastest within an XCD chunk.
    int nwg = gm * 20;
    int f = blockIdx.x;
    int q = nwg >> 3, r = nwg & 7;
    int xcd = f & 7, rank = f >> 3;
    int wg = (xcd < r ? xcd * (q + 1) : r * (q + 1) + (xcd - r) * q) + rank;
    int by = wg % 20;
    int bx = wg / 20;
    long rowTile = (long)bx * 256;
    int n0 = by * 256;

    // stage sources (granule decode): wave w -> rowblock w; lane -> kq,row.
    const u16* srcS[4];
    {
        int grow = w * 16 + (lane & 15);
        int gku  = (lane >> 4) * 8;
        srcS[0] = A  + (rowTile + grow) * K2 + gku;          // A0
        srcS[1] = A  + (rowTile + 128 + grow) * K2 + gku;    // A1
        srcS[2] = BT + (long)(n0 + grow) * K2 + gku;         // B0
        srcS[3] = BT + (long)(n0 + 128 + grow) * K2 + gku;   // B1
    }

    // fragment read offsets (u16): slot + rb*1KB + lane*16B (ks adds 4096 u16)
    int aOffP[8];
#pragma unroll
    for (int mt = 0; mt < 8; ++mt) {
        int hh = mt >> 2;                       // A half -> slot 0/1
        int rb = wm * 4 + (mt & 3);             // rowblock within half
        aOffP[mt] = hh * 8192 + rb * 512 + lane * 8;
    }
    int bOffP[4];
#pragma unroll
    for (int nt = 0; nt < 4; ++nt) {
        int hh = nt >> 1;                       // B half -> slot 2/3
        int rb = wn * 2 + (nt & 1);
        bOffP[nt] = 16384 + hh * 8192 + rb * 512 + lane * 8;
    }

    floatx4 acc[8][4];
#pragma unroll
    for (int mt = 0; mt < 8; ++mt)
#pragma unroll
        for (int nt = 0; nt < 4; ++nt)
            acc[mt][nt] = (floatx4){0.f, 0.f, 0.f, 0.f};

    short8 aF[2][4], b0F[2][2], b1F[2][2];

    // prologue: stage tile 0 into dbuf 0 in consume order A0,B0,B1,A1
    GP_STAGE(0, 0, 0);
    GP_STAGE(0, 0, 2);
    GP_STAGE(0, 0, 3);
    GP_STAGE(0, 0, 1);

    for (int t = 0; t < 31; ++t) {
        GP_TILE(t, t & 1, 0);
    }
    GP_TILE(31, 1, 1);

    // ---- epilogue: LDS round-trip, 4 slabs of 64 rows, coalesced float4 ----
    __syncthreads();
    float* epi = (float*)lds;                   // 64 x 260 fp32
#pragma unroll
    for (int s = 0; s < 4; ++s) {
        if (wm == (s & 1)) {
            int mtb = (s >> 1) * 4;
#pragma unroll
            for (int mi = 0; mi < 4; ++mi) {
#pragma unroll
                for (int rr = 0; rr < 4; ++rr) {
                    int lrow = mi * 16 + (lane >> 4) * 4 + rr;
#pragma unroll
                    for (int nt = 0; nt < 4; ++nt) {
                        int col = (nt >> 1) * 128 + wn * 32 + (nt & 1) * 16 + (lane & 15);
                        epi[lrow * 260 + col] = acc[mtb + mi][nt][rr];
                    }
                }
            }
        }
        __syncthreads();
        long gr0 = rowTile + s * 64;
#pragma unroll
        for (int k = 0; k < 8; ++k) {
            int f4 = tid + k * 512;             // 4096 slots = 64 rows x 64 float4
            int row = f4 >> 6, c4 = f4 & 63;
            float4 v = *(const float4*)&epi[row * 260 + c4 * 4];
            *(float4*)&G[(gr0 + row) * NTOT + n0 + c4 * 4] = v;
        }
        __syncthreads();
    }
}

#undef GP_STAGE
#undef GP_MFMA
#undef GP_TILE

// ---- gates (float4): c = sig(i)tanh(ck)+sig(fl)cl+sig(fr)cr; h = sig(o)tanh(c) ----
__global__ void gates(const float* __restrict__ G, const float* __restrict__ bio,
                      const float* __restrict__ bfl, const float* __restrict__ bfr,
                      const void* __restrict__ c_in, void* __restrict__ c_out, int c_bf16,
                      float* __restrict__ outF, u16* __restrict__ hnext,
                      int lp, int level_off, int row0, int mc) {
    int idx = blockIdx.x * 256 + threadIdx.x;
    int j = idx >> 8;
    if (j >= mc) return;
    int d = (idx & 255) * 4;
    int J = row0 + j;
    int b = J >> lp, p = J & ((1 << lp) - 1);
    long gb = (long)j * NTOT;
    float4 gi = *(const float4*)&G[gb + d];
    float4 go = *(const float4*)&G[gb + 1024 + d];
    float4 gc = *(const float4*)&G[gb + 2048 + d];
    float4 gl = *(const float4*)&G[gb + 3072 + d];
    float4 gr = *(const float4*)&G[gb + 4096 + d];
    float4 bi = *(const float4*)&bio[d];
    float4 bo = *(const float4*)&bio[1024 + d];
    float4 bc = *(const float4*)&bio[2048 + d];
    float4 bl = *(const float4*)&bfl[d];
    float4 br = *(const float4*)&bfr[d];
    float clv[4] = {0.f, 0.f, 0.f, 0.f}, crv[4] = {0.f, 0.f, 0.f, 0.f};
    if (c_in) {
        long cb = ((long)b * (2 << lp) + 2 * p) * H + d;
        if (c_bf16) {
            uint2 ul = *(const uint2*)((const u16*)c_in + cb);
            uint2 ur = *(const uint2*)((const u16*)c_in + cb + H);
            clv[0] = bf2f((u16)ul.x); clv[1] = bf2f((u16)(ul.x >> 16));
            clv[2] = bf2f((u16)ul.y); clv[3] = bf2f((u16)(ul.y >> 16));
            crv[0] = bf2f((u16)ur.x); crv[1] = bf2f((u16)(ur.x >> 16));
            crv[2] = bf2f((u16)ur.y); crv[3] = bf2f((u16)(ur.y >> 16));
        } else {
            float4 l4 = *(const float4*)((const float*)c_in + cb);
            float4 r4 = *(const float4*)((const float*)c_in + cb + H);
            clv[0] = l4.x; clv[1] = l4.y; clv[2] = l4.z; clv[3] = l4.w;
            crv[0] = r4.x; crv[1] = r4.y; crv[2] = r4.z; crv[3] = r4.w;
        }
    }
    const float* fgi = (const float*)&gi; const float* fgo = (const float*)&go;
    const float* fgc = (const float*)&gc; const float* fgl = (const float*)&gl;
    const float* fgr = (const float*)&gr;
    const float* fbi = (const float*)&bi; const float* fbo = (const float*)&bo;
    const float* fbc = (const float*)&bc; const float* fbl = (const float*)&bl;
    const float* fbr = (const float*)&br;
    float cv[4], hv[4];
    int has_c = (c_in != nullptr);
#pragma unroll
    for (int qq = 0; qq < 4; ++qq) {
        float c = sigf(fgi[qq] + fbi[qq]) * tanh_(fgc[qq] + fbc[qq]);
        if (has_c)
            c += sigf(fgl[qq] + fbl[qq]) * clv[qq] + sigf(fgr[qq] + fbr[qq]) * crv[qq];
        cv[qq] = c;
        hv[qq] = sigf(fgo[qq] + fbo[qq]) * tanh_(c);
    }
    long co = (long)J * H + d;
    if (c_bf16) {
        uint2 oc; oc.x = pk2(cv[0], cv[1]); oc.y = pk2(cv[2], cv[3]);
        *(uint2*)((u16*)c_out + co) = oc;
    } else {
        *(float4*)((float*)c_out + co) = make_float4(cv[0], cv[1], cv[2], cv[3]);
    }
    long oi = ((long)b * 255 + level_off + p) * H + d;
    *(float4*)&outF[oi] = make_float4(hv[0], hv[1], hv[2], hv[3]);
    uint2 oh; oh.x = pk2(hv[0], hv[1]); oh.y = pk2(hv[2], hv[3]);
    *(uint2*)(hnext + (long)J * H + d) = oh;
}

__global__ void root_copy(const float* __restrict__ outF, const void* __restrict__ c_root,
                          int c_bf16, float* __restrict__ tail) {
    int idx = blockIdx.x * 256 + threadIdx.x;   // 131072
    if (idx < 65536) {
        int b = idx >> 10, d = idx & 1023;
        tail[idx] = outF[((long)b * 255 + 254) * H + d];
    } else {
        int i2 = idx - 65536;
        tail[idx] = c_bf16 ? bf2f(((const u16*)c_root)[i2]) : ((const float*)c_root)[i2];
    }
}

extern "C" void kernel_launch(void* const* d_in, const int* in_sizes, int n_in,
                              void* d_out, int out_size, void* d_ws, size_t ws_size,
                              hipStream_t stream) {
    const int* tokens = (const int*)d_in[0];
    const float* emb = (const float*)d_in[1];
    const float* Wio = (const float*)d_in[2];
    const float* bio = (const float*)d_in[3];
    const float* Uio = (const float*)d_in[4];
    const float* Wfl = (const float*)d_in[5];
    const float* bfl = (const float*)d_in[6];
    const float* Ufl = (const float*)d_in[7];
    const float* Wfr = (const float*)d_in[8];
    const float* bfr = (const float*)d_in[9];
    const float* Ufr = (const float*)d_in[10];
    float* outF = (float*)d_out;

    // ---- ws carve (adaptive) ----
    char* ws = (char*)d_ws;
    size_t off = 0;
    u16* WT   = (u16*)(ws + off); off += (size_t)NTOT * K2 * 2;        // 20.97 MB
    u16* leaf = (u16*)(ws + off); off += (size_t)BATCH * 256 * H * 2;  // 33.55 MB
    u16* hE   = (u16*)(ws + off); off += (size_t)8192 * H * 2;         // 16.78 MB
    u16* hO   = (u16*)(ws + off); off += (size_t)4096 * H * 2;         //  8.39 MB
    size_t cEf = (size_t)8192 * H, cOf = (size_t)4096 * H;             // elements
    int c_bf16 = (ws_size >= off + (cEf + cOf) * 4 + (size_t)512 * NTOT * 4) ? 0 : 1;
    size_t csz = c_bf16 ? 2 : 4;
    void* cE = (void*)(ws + off); off += cEf * csz;
    void* cO = (void*)(ws + off); off += cOf * csz;
    size_t avail = (ws_size > off) ? (ws_size - off) : 0;
    long Grows = (long)(avail / ((size_t)NTOT * 4));
    if (Grows > 8192) Grows = 8192;
    Grows &= ~255L;
    if (Grows < 128) Grows = 128;
    float* G = (float*)(ws + off);

    pack_weights<<<dim3(64, 160), 256, 0, stream>>>(Wio, Uio, Wfl, Ufl, Wfr, Ufr, WT);
    leaf_pack<<<16384, 256, 0, stream>>>(tokens, emb, leaf);

    const int off_out[8] = {0, 128, 192, 224, 240, 248, 252, 254};
    for (int li = 0; li < 8; ++li) {
        int lp = 7 - li;
        long m = (long)BATCH << lp;
        const u16* Acur = (li == 0) ? leaf : ((li & 1) ? hE : hO);
        u16* hnext = (li & 1) ? hO : hE;
        const void* c_in = (li == 0) ? nullptr : ((li & 1) ? cE : cO);
        void* c_out = (li & 1) ? cO : cE;
        for (long row0 = 0; row0 < m; row0 += Grows) {
            int mc = (int)((m - row0 > Grows) ? Grows : (m - row0));
            if (mc >= 1024 && (mc & 255) == 0) {
                int gm = mc >> 8;
                gemmP<<<gm * 20, 512, 0, stream>>>(Acur + row0 * K2, WT, G, gm);
            } else {
                dim3 grid((mc + BM - 1) / BM, NTOT / BN);
                gemm_bt<<<grid, 256, 0, stream>>>(Acur + row0 * K2, WT, G, mc);
            }
            gates<<<mc, 256, 0, stream>>>(G, bio, bfl, bfr, c_in, c_out, c_bf16,
                                          outF, hnext, lp, off_out[li], (int)row0, mc);
        }
    }
    root_copy<<<512, 256, 0, stream>>>(outF, cO, c_bf16, outF + (size_t)BATCH * 255 * H);
}

// Round 5
// 939.909 us; speedup vs baseline: 1.0645x; 1.0645x over previous
//
#include <hip/hip_runtime.h>
#include <stdint.h>

#define H     1024
#define K2    2048
#define NTOT  5120
#define BATCH 64
#define BM 128
#define BN 128
#define BK 64

typedef unsigned short u16;
typedef __attribute__((ext_vector_type(8))) short short8;
typedef __attribute__((ext_vector_type(4))) float floatx4;

__device__ __forceinline__ float bf2f(u16 u) {
    return __uint_as_float(((uint32_t)u) << 16);
}
__device__ __forceinline__ u16 f2bf(float f) {
    uint32_t u = __float_as_uint(f);
    u += 0x7fffu + ((u >> 16) & 1u);
    return (u16)(u >> 16);
}
__device__ __forceinline__ uint32_t pk2(float lo, float hi) {
    return (uint32_t)f2bf(lo) | ((uint32_t)f2bf(hi) << 16);
}
__device__ __forceinline__ float sigf(float x) {
    return 1.0f / (1.0f + __expf(-x));
}
__device__ __forceinline__ float tanh_(float x) {
    float e = __expf(-2.0f * fabsf(x));
    float r = (1.0f - e) / (1.0f + e);
    return copysignf(r, x);
}

// ---- pack weights (fp32 in) -> bf16 WT[n][k]; k<1024 from W, else U ----
__global__ void pack_weights(const float* __restrict__ Wio, const float* __restrict__ Uio,
                             const float* __restrict__ Wfl, const float* __restrict__ Ufl,
                             const float* __restrict__ Wfr, const float* __restrict__ Ufr,
                             u16* __restrict__ WT) {
    __shared__ u16 tile[32][33];
    int k0 = blockIdx.x * 32;
    int n0 = blockIdx.y * 32;
    const float *Wp, *Up; int ncols, nloc;
    if (n0 < 3072)      { Wp = Wio; Up = Uio; ncols = 3072; nloc = n0; }
    else if (n0 < 4096) { Wp = Wfl; Up = Ufl; ncols = 1024; nloc = n0 - 3072; }
    else                { Wp = Wfr; Up = Ufr; ncols = 1024; nloc = n0 - 4096; }
    int t = threadIdx.x;
    int c = t & 31, r = t >> 5;
#pragma unroll
    for (int i = 0; i < 4; ++i) {
        int rr = r + i * 8;
        int k = k0 + rr;
        float v = (k < 1024) ? Wp[(long)k * ncols + nloc + c]
                             : Up[(long)(k - 1024) * ncols + nloc + c];
        tile[rr][c] = f2bf(v);
    }
    __syncthreads();
#pragma unroll
    for (int i = 0; i < 4; ++i) {
        int rr = r + i * 8;
        WT[(long)(n0 + rr) * K2 + k0 + c] = tile[c][rr];
    }
}

// ---- leaf gather + fp32->bf16: leaf[node][d] = emb[tokens[node]][d] ----
__global__ void leaf_pack(const int* __restrict__ tokens, const float* __restrict__ emb,
                          u16* __restrict__ leaf) {
    int idx = blockIdx.x * 256 + threadIdx.x;   // 16384 blocks -> 4,194,304 float4
    int node = idx >> 8;
    int d4 = idx & 255;
    int tok = tokens[node];
    float4 v = ((const float4*)emb)[(long)tok * 256 + d4];
    uint2 o; o.x = pk2(v.x, v.y); o.y = pk2(v.z, v.w);
    ((uint2*)leaf)[(long)node * 256 + d4] = o;
}

// ---- GEMM (m97 structure, 128x128) for small row counts ----
__global__ void gemm_bt(const u16* __restrict__ A, const u16* __restrict__ BT,
                        float* __restrict__ G, int mc) {
    __shared__ __align__(16) u16 AsBs[16896];   // 33,792 B; K-loop: As|Bs, epilogue: epi
    u16* As = AsBs;
    u16* Bs = AsBs + 8192;
    float* epi = (float*)AsBs;                  // 64 x 132 fp32
    int tid  = threadIdx.x;
    int lane = tid & 63;
    int w    = tid >> 6;
    int wm   = w >> 1, wn = w & 1;
    int rowTile = blockIdx.x * BM;
    int n0      = blockIdx.y * BN;

    const u16* asrc[4];
    const u16* bsrc[4];
#pragma unroll
    for (int cc = 0; cc < 4; ++cc) {
        int r = cc * 32 + w * 8 + (lane >> 3);
        int j = rowTile + r; if (j >= mc) j = mc - 1;
        asrc[cc] = A + (long)j * K2 + (lane & 7) * 8;
        bsrc[cc] = BT + (long)(n0 + r) * K2 + (lane & 7) * 8;
    }

    floatx4 acc[4][4];
#pragma unroll
    for (int mt = 0; mt < 4; ++mt)
#pragma unroll
        for (int nt = 0; nt < 4; ++nt)
            acc[mt][nt] = (floatx4){0.f, 0.f, 0.f, 0.f};

    for (int k0 = 0; k0 < K2; k0 += BK) {
#pragma unroll
        for (int cc = 0; cc < 4; ++cc) {
            __builtin_amdgcn_global_load_lds(
                (const __attribute__((address_space(1))) void*)(asrc[cc] + k0),
                (__attribute__((address_space(3))) void*)(As + cc * 2048 + w * 512), 16, 0, 0);
            __builtin_amdgcn_global_load_lds(
                (const __attribute__((address_space(1))) void*)(bsrc[cc] + k0),
                (__attribute__((address_space(3))) void*)(Bs + cc * 2048 + w * 512), 16, 0, 0);
        }
        __syncthreads();
#pragma unroll
        for (int kb = 0; kb < 2; ++kb) {
            int kfo = kb * 32 + (lane >> 4) * 8;
            short8 af[4], bfv[4];
#pragma unroll
            for (int mt = 0; mt < 4; ++mt)
                af[mt] = *(const short8*)&As[(wm * 64 + mt * 16 + (lane & 15)) * BK + kfo];
#pragma unroll
            for (int nt = 0; nt < 4; ++nt)
                bfv[nt] = *(const short8*)&Bs[(wn * 64 + nt * 16 + (lane & 15)) * BK + kfo];
#pragma unroll
            for (int mt = 0; mt < 4; ++mt)
#pragma unroll
                for (int nt = 0; nt < 4; ++nt)
                    acc[mt][nt] = __builtin_amdgcn_mfma_f32_16x16x32_bf16(
                        af[mt], bfv[nt], acc[mt][nt], 0, 0, 0);
        }
        __syncthreads();
    }

    // ---- epilogue: LDS round-trip -> fully coalesced float4 stores ----
#pragma unroll
    for (int s = 0; s < 2; ++s) {
        if (wm == s) {
#pragma unroll
            for (int mt = 0; mt < 4; ++mt)
#pragma unroll
                for (int r = 0; r < 4; ++r) {
                    int lrow = mt * 16 + (lane >> 4) * 4 + r;
#pragma unroll
                    for (int nt = 0; nt < 4; ++nt)
                        epi[lrow * 132 + wn * 64 + nt * 16 + (lane & 15)] = acc[mt][nt][r];
                }
        }
        __syncthreads();
        int gr0 = rowTile + s * 64;
#pragma unroll
        for (int k = 0; k < 8; ++k) {
            int f4 = tid + k * 256;     // 0..2047 float4 slots = 64 rows x 32
            int row = f4 >> 5, c4 = f4 & 31;
            if (gr0 + row < mc) {
                float4 v = *(const float4*)&epi[row * 132 + c4 * 4];
                *(float4*)&G[(long)(gr0 + row) * NTOT + n0 + c4 * 4] = v;
            }
        }
        __syncthreads();
    }
}

// ==== FUSED 256-row x 64-d GEMM+gates: no G matrix ===========================
// Block owns rows [rowTile,+256) x d-cols [d0,+64) for ALL 5 gate strips:
// B-tile = WT rows {g*1024+d0 .. +63 | g=0..4} (320 rows). Each lane then holds
// i,o,ck,fl,fr for its (row,d) in acc registers -> LSTM math in-epilogue.
// 8 waves = 4M x 2D: wm=w>>1 (64-row slab), wd=w&1 (32-d slab).
// Per-wave acc: 4 m-frags x 10 n-frags (5 gates x 2 subs) = 160 VGPRs.
// LDS/tile 72KB: A = [half:2][ks:2](128r x 64B) = 32KB, B = [g:5][ks:2](64r x 64B)
// = 40KB; dbuf 144KB. Row layout: byte = row*64 + ((chunk ^ ((row>>1)&3))<<4):
// frag ds_read_b128 = 2 lanes/bank-quad (optimal), stage global src = 4 rows x
// 64B contiguous per quarter-wave. Stage = 9 calls/tile (A:4, B:5), linear LDS
// dest (wave-uniform + lane*16), inverse(=same XOR) swizzled global source.
// Pipeline per tile: barrier; STAGE(t+1 -> other buf); vmcnt(9); barrier;
// compute (2 ks x 5 g clusters of 8 MFMA). Last tile: vmcnt(0).
#define SWZ2(r) (((r) >> 1) & 3)

__global__ __launch_bounds__(512, 2) void gemmF(const u16* __restrict__ A,
                                                const u16* __restrict__ BT,
                                                const float* __restrict__ bio,
                                                const float* __restrict__ bfl,
                                                const float* __restrict__ bfr,
                                                const void* __restrict__ c_in,
                                                void* __restrict__ c_out, int c_bf16,
                                                float* __restrict__ outF,
                                                u16* __restrict__ hnext,
                                                int lp, int level_off, int gm) {
    __shared__ __align__(16) u16 lds[2 * 36864];    // 144 KiB
    const int tid  = threadIdx.x;
    const int lane = tid & 63;
    const int w    = tid >> 6;
    const int wm   = w >> 1;    // 0..3
    const int wd   = w & 1;     // 0..1

    // XCD-bijective swizzle; row-tile fastest within chunk (share B strips in L2)
    int nwg = gm * 16;
    int f = blockIdx.x;
    int q = nwg >> 3, r = nwg & 7;
    int xcd = f & 7, rank = f >> 3;
    int wg = (xcd < r ? xcd * (q + 1) : r * (q + 1) + (xcd - r) * q) + rank;
    int by = wg / gm;           // d-tile 0..15
    int bx = wg % gm;
    long rowTile = (long)bx * 256;
    int d0 = by * 64;

    // ---- stage sources (per-thread). Dest is linear tid*16B per call. ----
    // A call c: half hc=c>>1, ks=c&1; region row = w*16 + (lane>>2).
    const u16* srcA[4];
    {
        int rr_ = w * 16 + (lane >> 2);
        int ck_ = ((lane & 3) ^ SWZ2(rr_)) * 8;
#pragma unroll
        for (int c = 0; c < 4; ++c)
            srcA[c] = A + (rowTile + (c >> 1) * 128 + rr_) * (long)K2 + (c & 1) * 32 + ck_;
    }
    // B call g: strip g; ks = w&1; strip row = (w>>1)*16 + (lane>>2).
    const u16* srcB[5];
    {
        int sr_ = (w >> 1) * 16 + (lane >> 2);
        int ck_ = ((lane & 3) ^ SWZ2(sr_)) * 8;
#pragma unroll
        for (int g = 0; g < 5; ++g)
            srcB[g] = BT + (long)(g * 1024 + d0 + sr_) * K2 + (w & 1) * 32 + ck_;
    }

    // ---- fragment read offsets (u16), ks=0; A: +4096 per ks, B: +2048 ----
    const int qv = lane >> 4;
    int rA[4];
#pragma unroll
    for (int mf = 0; mf < 4; ++mf) {
        int rl = (wm & 1) * 64 + mf * 16 + (lane & 15);     // row in 128-row half
        rA[mf] = (wm >> 1) * 8192 + rl * 32 + ((qv ^ SWZ2(rl)) * 8);
    }
    int rB[2];
#pragma unroll
    for (int sub = 0; sub < 2; ++sub) {
        int rb = wd * 32 + sub * 16 + (lane & 15);          // row in 64-row strip
        rB[sub] = rb * 32 + ((qv ^ SWZ2(rb)) * 8);
    }

    floatx4 acc[4][10];
#pragma unroll
    for (int mf = 0; mf < 4; ++mf)
#pragma unroll
        for (int nf = 0; nf < 10; ++nf)
            acc[mf][nf] = (floatx4){0.f, 0.f, 0.f, 0.f};

#define GF_STAGE(TT, DD)                                                             \
    do {                                                                             \
        _Pragma("unroll")                                                            \
        for (int c = 0; c < 4; ++c)                                                  \
            __builtin_amdgcn_global_load_lds(                                        \
                (const __attribute__((address_space(1))) void*)(srcA[c] + (TT) * 64),\
                (__attribute__((address_space(3))) void*)(lds + (DD) * 36864 + (c >> 1) * 8192 + (c & 1) * 4096 + tid * 8), 16, 0, 0); \
        _Pragma("unroll")                                                            \
        for (int g = 0; g < 5; ++g)                                                  \
            __builtin_amdgcn_global_load_lds(                                        \
                (const __attribute__((address_space(1))) void*)(srcB[g] + (TT) * 64),\
                (__attribute__((address_space(3))) void*)(lds + (DD) * 36864 + 16384 + g * 4096 + (w & 1) * 2048 + (w >> 1) * 512 + lane * 8), 16, 0, 0); \
    } while (0)

    // prologue
    GF_STAGE(0, 0);

    for (int t = 0; t < 32; ++t) {
        int d = t & 1;
        asm volatile("s_barrier" ::: "memory");     // reads of buf d^1 done
        if (t < 31) {
            GF_STAGE(t + 1, d ^ 1);
            asm volatile("s_waitcnt vmcnt(9)" ::: "memory");    // tile t landed
        } else {
            asm volatile("s_waitcnt vmcnt(0)" ::: "memory");
        }
        asm volatile("s_barrier" ::: "memory");     // all waves: tile t ready
        const u16* bufD = lds + d * 36864;
#pragma unroll
        for (int ks = 0; ks < 2; ++ks) {
            short8 aF[4];
#pragma unroll
            for (int mf = 0; mf < 4; ++mf)
                aF[mf] = *(const short8*)&bufD[rA[mf] + ks * 4096];
#pragma unroll
            for (int g = 0; g < 5; ++g) {
                short8 bF[2];
#pragma unroll
                for (int sub = 0; sub < 2; ++sub)
                    bF[sub] = *(const short8*)&bufD[16384 + g * 4096 + ks * 2048 + rB[sub]];
                __builtin_amdgcn_s_setprio(1);
#pragma unroll
                for (int mf = 0; mf < 4; ++mf)
#pragma unroll
                    for (int sub = 0; sub < 2; ++sub)
                        acc[mf][g * 2 + sub] = __builtin_amdgcn_mfma_f32_16x16x32_bf16(
                            aF[mf], bF[sub], acc[mf][g * 2 + sub], 0, 0, 0);
                __builtin_amdgcn_s_setprio(0);
            }
        }
    }
#undef GF_STAGE

    // ---- fused epilogue: LSTM gate math straight from acc ----
    float bI[2], bO[2], bC[2], bL[2], bR[2];
    int dsub[2];
#pragma unroll
    for (int sub = 0; sub < 2; ++sub) {
        int dd = d0 + wd * 32 + sub * 16 + (lane & 15);
        dsub[sub] = dd;
        bI[sub] = bio[dd]; bO[sub] = bio[1024 + dd]; bC[sub] = bio[2048 + dd];
        bL[sub] = bfl[dd]; bR[sub] = bfr[dd];
    }
    int pmask = (1 << lp) - 1;
    int has_c = (c_in != nullptr);
#pragma unroll
    for (int mf = 0; mf < 4; ++mf) {
#pragma unroll
        for (int rr = 0; rr < 4; ++rr) {
            int row = wm * 64 + mf * 16 + (lane >> 4) * 4 + rr;
            long J = rowTile + row;
            int b = (int)(J >> lp), p = (int)(J & pmask);
            long ho = ((long)b * 255 + level_off + p) * H;
#pragma unroll
            for (int sub = 0; sub < 2; ++sub) {
                int dd = dsub[sub];
                float i_  = acc[mf][0 + sub][rr] + bI[sub];
                float o_  = acc[mf][2 + sub][rr] + bO[sub];
                float ck_ = acc[mf][4 + sub][rr] + bC[sub];
                float cv = sigf(i_) * tanh_(ck_);
                if (has_c) {
                    float fl_ = sigf(acc[mf][6 + sub][rr] + bL[sub]);
                    float fr_ = sigf(acc[mf][8 + sub][rr] + bR[sub]);
                    float cl, cr;
                    if (c_bf16) {
                        cl = bf2f(__builtin_nontemporal_load(
                                 (const u16*)c_in + (2 * J) * H + dd));
                        cr = bf2f(__builtin_nontemporal_load(
                                 (const u16*)c_in + (2 * J + 1) * H + dd));
                    } else {
                        cl = __builtin_nontemporal_load(
                                 (const float*)c_in + (2 * J) * H + dd);
                        cr = __builtin_nontemporal_load(
                                 (const float*)c_in + (2 * J + 1) * H + dd);
                    }
                    cv += fl_ * cl + fr_ * cr;
                }
                float hv = sigf(o_) * tanh_(cv);
                __builtin_nontemporal_store(hv, &outF[ho + dd]);
                if (c_bf16)
                    __builtin_nontemporal_store(f2bf(cv), (u16*)c_out + J * H + dd);
                else
                    __builtin_nontemporal_store(cv, (float*)c_out + J * H + dd);
                __builtin_nontemporal_store(f2bf(hv), hnext + J * H + dd);
            }
        }
    }
}

// ---- gates (float4): c = sig(i)tanh(ck)+sig(fl)cl+sig(fr)cr; h = sig(o)tanh(c) ----
__global__ void gates(const float* __restrict__ G, const float* __restrict__ bio,
                      const float* __restrict__ bfl, const float* __restrict__ bfr,
                      const void* __restrict__ c_in, void* __restrict__ c_out, int c_bf16,
                      float* __restrict__ outF, u16* __restrict__ hnext,
                      int lp, int level_off, int row0, int mc) {
    int idx = blockIdx.x * 256 + threadIdx.x;
    int j = idx >> 8;
    if (j >= mc) return;
    int d = (idx & 255) * 4;
    int J = row0 + j;
    int b = J >> lp, p = J & ((1 << lp) - 1);
    long gb = (long)j * NTOT;
    float4 gi = *(const float4*)&G[gb + d];
    float4 go = *(const float4*)&G[gb + 1024 + d];
    float4 gc = *(const float4*)&G[gb + 2048 + d];
    float4 gl = *(const float4*)&G[gb + 3072 + d];
    float4 gr = *(const float4*)&G[gb + 4096 + d];
    float4 bi = *(const float4*)&bio[d];
    float4 bo = *(const float4*)&bio[1024 + d];
    float4 bc = *(const float4*)&bio[2048 + d];
    float4 bl = *(const float4*)&bfl[d];
    float4 br = *(const float4*)&bfr[d];
    float clv[4] = {0.f, 0.f, 0.f, 0.f}, crv[4] = {0.f, 0.f, 0.f, 0.f};
    if (c_in) {
        long cb = ((long)b * (2 << lp) + 2 * p) * H + d;
        if (c_bf16) {
            uint2 ul = *(const uint2*)((const u16*)c_in + cb);
            uint2 ur = *(const uint2*)((const u16*)c_in + cb + H);
            clv[0] = bf2f((u16)ul.x); clv[1] = bf2f((u16)(ul.x >> 16));
            clv[2] = bf2f((u16)ul.y); clv[3] = bf2f((u16)(ul.y >> 16));
            crv[0] = bf2f((u16)ur.x); crv[1] = bf2f((u16)(ur.x >> 16));
            crv[2] = bf2f((u16)ur.y); crv[3] = bf2f((u16)(ur.y >> 16));
        } else {
            float4 l4 = *(const float4*)((const float*)c_in + cb);
            float4 r4 = *(const float4*)((const float*)c_in + cb + H);
            clv[0] = l4.x; clv[1] = l4.y; clv[2] = l4.z; clv[3] = l4.w;
            crv[0] = r4.x; crv[1] = r4.y; crv[2] = r4.z; crv[3] = r4.w;
        }
    }
    const float* fgi = (const float*)&gi; const float* fgo = (const float*)&go;
    const float* fgc = (const float*)&gc; const float* fgl = (const float*)&gl;
    const float* fgr = (const float*)&gr;
    const float* fbi = (const float*)&bi; const float* fbo = (const float*)&bo;
    const float* fbc = (const float*)&bc; const float* fbl = (const float*)&bl;
    const float* fbr = (const float*)&br;
    float cv[4], hv[4];
    int has_c = (c_in != nullptr);
#pragma unroll
    for (int qq = 0; qq < 4; ++qq) {
        float c = sigf(fgi[qq] + fbi[qq]) * tanh_(fgc[qq] + fbc[qq]);
        if (has_c)
            c += sigf(fgl[qq] + fbl[qq]) * clv[qq] + sigf(fgr[qq] + fbr[qq]) * crv[qq];
        cv[qq] = c;
        hv[qq] = sigf(fgo[qq] + fbo[qq]) * tanh_(c);
    }
    long co = (long)J * H + d;
    if (c_bf16) {
        uint2 oc; oc.x = pk2(cv[0], cv[1]); oc.y = pk2(cv[2], cv[3]);
        *(uint2*)((u16*)c_out + co) = oc;
    } else {
        *(float4*)((float*)c_out + co) = make_float4(cv[0], cv[1], cv[2], cv[3]);
    }
    long oi = ((long)b * 255 + level_off + p) * H + d;
    *(float4*)&outF[oi] = make_float4(hv[0], hv[1], hv[2], hv[3]);
    uint2 oh; oh.x = pk2(hv[0], hv[1]); oh.y = pk2(hv[2], hv[3]);
    *(uint2*)(hnext + (long)J * H + d) = oh;
}

__global__ void root_copy(const float* __restrict__ outF, const void* __restrict__ c_root,
                          int c_bf16, float* __restrict__ tail) {
    int idx = blockIdx.x * 256 + threadIdx.x;   // 131072
    if (idx < 65536) {
        int b = idx >> 10, d = idx & 1023;
        tail[idx] = outF[((long)b * 255 + 254) * H + d];
    } else {
        int i2 = idx - 65536;
        tail[idx] = c_bf16 ? bf2f(((const u16*)c_root)[i2]) : ((const float*)c_root)[i2];
    }
}

extern "C" void kernel_launch(void* const* d_in, const int* in_sizes, int n_in,
                              void* d_out, int out_size, void* d_ws, size_t ws_size,
                              hipStream_t stream) {
    const int* tokens = (const int*)d_in[0];
    const float* emb = (const float*)d_in[1];
    const float* Wio = (const float*)d_in[2];
    const float* bio = (const float*)d_in[3];
    const float* Uio = (const float*)d_in[4];
    const float* Wfl = (const float*)d_in[5];
    const float* bfl = (const float*)d_in[6];
    const float* Ufl = (const float*)d_in[7];
    const float* Wfr = (const float*)d_in[8];
    const float* bfr = (const float*)d_in[9];
    const float* Ufr = (const float*)d_in[10];
    float* outF = (float*)d_out;

    // ---- ws carve (adaptive) ----
    char* ws = (char*)d_ws;
    size_t off = 0;
    u16* WT   = (u16*)(ws + off); off += (size_t)NTOT * K2 * 2;        // 20.97 MB
    u16* leaf = (u16*)(ws + off); off += (size_t)BATCH * 256 * H * 2;  // 33.55 MB
    u16* hE   = (u16*)(ws + off); off += (size_t)8192 * H * 2;         // 16.78 MB
    u16* hO   = (u16*)(ws + off); off += (size_t)4096 * H * 2;         //  8.39 MB
    size_t cEf = (size_t)8192 * H, cOf = (size_t)4096 * H;             // elements
    int c_bf16 = (ws_size >= off + (cEf + cOf) * 4 + (size_t)512 * NTOT * 4) ? 0 : 1;
    size_t csz = c_bf16 ? 2 : 4;
    void* cE = (void*)(ws + off); off += cEf * csz;
    void* cO = (void*)(ws + off); off += cOf * csz;
    size_t avail = (ws_size > off) ? (ws_size - off) : 0;
    long Grows = (long)(avail / ((size_t)NTOT * 4));
    if (Grows > 512) Grows = 512;           // legacy path only handles m <= 512
    Grows &= ~127L;
    if (Grows < 128) Grows = 128;
    float* G = (float*)(ws + off);

    pack_weights<<<dim3(64, 160), 256, 0, stream>>>(Wio, Uio, Wfl, Ufl, Wfr, Ufr, WT);
    leaf_pack<<<16384, 256, 0, stream>>>(tokens, emb, leaf);

    const int off_out[8] = {0, 128, 192, 224, 240, 248, 252, 254};
    for (int li = 0; li < 8; ++li) {
        int lp = 7 - li;
        long m = (long)BATCH << lp;
        const u16* Acur = (li == 0) ? leaf : ((li & 1) ? hE : hO);
        u16* hnext = (li & 1) ? hO : hE;
        const void* c_in = (li == 0) ? nullptr : ((li & 1) ? cE : cO);
        void* c_out = (li & 1) ? cO : cE;
        if (m >= 1024) {
            int gm = (int)(m >> 8);
            gemmF<<<gm * 16, 512, 0, stream>>>(Acur, WT, bio, bfl, bfr,
                                               c_in, c_out, c_bf16, outF, hnext,
                                               lp, off_out[li], gm);
        } else {
            for (long row0 = 0; row0 < m; row0 += Grows) {
                int mc = (int)((m - row0 > Grows) ? Grows : (m - row0));
                dim3 grid((mc + BM - 1) / BM, NTOT / BN);
                gemm_bt<<<grid, 256, 0, stream>>>(Acur + row0 * K2, WT, G, mc);
                gates<<<mc, 256, 0, stream>>>(G, bio, bfl, bfr, c_in, c_out, c_bf16,
                                              outF, hnext, lp, off_out[li], (int)row0, mc);
            }
        }
    }
    root_copy<<<512, 256, 0, stream>>>(outF, cO, c_bf16, outF + (size_t)BATCH * 255 * H);
}

// Round 6
// 862.082 us; speedup vs baseline: 1.1607x; 1.0903x over previous
//
#include <hip/hip_runtime.h>
#include <stdint.h>

#define H     1024
#define K2    2048
#define NTOT  5120
#define BATCH 64
#define BM 128
#define BN 128
#define BK 64

typedef unsigned short u16;
typedef __attribute__((ext_vector_type(8))) short short8;
typedef __attribute__((ext_vector_type(4))) float floatx4;

__device__ __forceinline__ float bf2f(u16 u) {
    return __uint_as_float(((uint32_t)u) << 16);
}
__device__ __forceinline__ u16 f2bf(float f) {
    uint32_t u = __float_as_uint(f);
    u += 0x7fffu + ((u >> 16) & 1u);
    return (u16)(u >> 16);
}
__device__ __forceinline__ uint32_t pk2(float lo, float hi) {
    return (uint32_t)f2bf(lo) | ((uint32_t)f2bf(hi) << 16);
}
__device__ __forceinline__ float sigf(float x) {
    return 1.0f / (1.0f + __expf(-x));
}
__device__ __forceinline__ float tanh_(float x) {
    float e = __expf(-2.0f * fabsf(x));
    float r = (1.0f - e) / (1.0f + e);
    return copysignf(r, x);
}

// ---- pack weights (fp32 in) -> bf16 WT[n][k]; k<1024 from W, else U ----
__global__ void pack_weights(const float* __restrict__ Wio, const float* __restrict__ Uio,
                             const float* __restrict__ Wfl, const float* __restrict__ Ufl,
                             const float* __restrict__ Wfr, const float* __restrict__ Ufr,
                             u16* __restrict__ WT) {
    __shared__ u16 tile[32][33];
    int k0 = blockIdx.x * 32;
    int n0 = blockIdx.y * 32;
    const float *Wp, *Up; int ncols, nloc;
    if (n0 < 3072)      { Wp = Wio; Up = Uio; ncols = 3072; nloc = n0; }
    else if (n0 < 4096) { Wp = Wfl; Up = Ufl; ncols = 1024; nloc = n0 - 3072; }
    else                { Wp = Wfr; Up = Ufr; ncols = 1024; nloc = n0 - 4096; }
    int t = threadIdx.x;
    int c = t & 31, r = t >> 5;
#pragma unroll
    for (int i = 0; i < 4; ++i) {
        int rr = r + i * 8;
        int k = k0 + rr;
        float v = (k < 1024) ? Wp[(long)k * ncols + nloc + c]
                             : Up[(long)(k - 1024) * ncols + nloc + c];
        tile[rr][c] = f2bf(v);
    }
    __syncthreads();
#pragma unroll
    for (int i = 0; i < 4; ++i) {
        int rr = r + i * 8;
        WT[(long)(n0 + rr) * K2 + k0 + c] = tile[c][rr];
    }
}

// ---- leaf gather + fp32->bf16: leaf[node][d] = emb[tokens[node]][d] ----
__global__ void leaf_pack(const int* __restrict__ tokens, const float* __restrict__ emb,
                          u16* __restrict__ leaf) {
    int idx = blockIdx.x * 256 + threadIdx.x;   // 16384 blocks -> 4,194,304 float4
    int node = idx >> 8;
    int d4 = idx & 255;
    int tok = tokens[node];
    float4 v = ((const float4*)emb)[(long)tok * 256 + d4];
    uint2 o; o.x = pk2(v.x, v.y); o.y = pk2(v.z, v.w);
    ((uint2*)leaf)[(long)node * 256 + d4] = o;
}

// ---- GEMM (m97 structure, 128x128) for small row counts ----
__global__ void gemm_bt(const u16* __restrict__ A, const u16* __restrict__ BT,
                        float* __restrict__ G, int mc) {
    __shared__ __align__(16) u16 AsBs[16896];   // 33,792 B; K-loop: As|Bs, epilogue: epi
    u16* As = AsBs;
    u16* Bs = AsBs + 8192;
    float* epi = (float*)AsBs;                  // 64 x 132 fp32
    int tid  = threadIdx.x;
    int lane = tid & 63;
    int w    = tid >> 6;
    int wm   = w >> 1, wn = w & 1;
    int rowTile = blockIdx.x * BM;
    int n0      = blockIdx.y * BN;

    const u16* asrc[4];
    const u16* bsrc[4];
#pragma unroll
    for (int cc = 0; cc < 4; ++cc) {
        int r = cc * 32 + w * 8 + (lane >> 3);
        int j = rowTile + r; if (j >= mc) j = mc - 1;
        asrc[cc] = A + (long)j * K2 + (lane & 7) * 8;
        bsrc[cc] = BT + (long)(n0 + r) * K2 + (lane & 7) * 8;
    }

    floatx4 acc[4][4];
#pragma unroll
    for (int mt = 0; mt < 4; ++mt)
#pragma unroll
        for (int nt = 0; nt < 4; ++nt)
            acc[mt][nt] = (floatx4){0.f, 0.f, 0.f, 0.f};

    for (int k0 = 0; k0 < K2; k0 += BK) {
#pragma unroll
        for (int cc = 0; cc < 4; ++cc) {
            __builtin_amdgcn_global_load_lds(
                (const __attribute__((address_space(1))) void*)(asrc[cc] + k0),
                (__attribute__((address_space(3))) void*)(As + cc * 2048 + w * 512), 16, 0, 0);
            __builtin_amdgcn_global_load_lds(
                (const __attribute__((address_space(1))) void*)(bsrc[cc] + k0),
                (__attribute__((address_space(3))) void*)(Bs + cc * 2048 + w * 512), 16, 0, 0);
        }
        __syncthreads();
#pragma unroll
        for (int kb = 0; kb < 2; ++kb) {
            int kfo = kb * 32 + (lane >> 4) * 8;
            short8 af[4], bfv[4];
#pragma unroll
            for (int mt = 0; mt < 4; ++mt)
                af[mt] = *(const short8*)&As[(wm * 64 + mt * 16 + (lane & 15)) * BK + kfo];
#pragma unroll
            for (int nt = 0; nt < 4; ++nt)
                bfv[nt] = *(const short8*)&Bs[(wn * 64 + nt * 16 + (lane & 15)) * BK + kfo];
#pragma unroll
            for (int mt = 0; mt < 4; ++mt)
#pragma unroll
                for (int nt = 0; nt < 4; ++nt)
                    acc[mt][nt] = __builtin_amdgcn_mfma_f32_16x16x32_bf16(
                        af[mt], bfv[nt], acc[mt][nt], 0, 0, 0);
        }
        __syncthreads();
    }

    // ---- epilogue: LDS round-trip -> fully coalesced float4 stores ----
#pragma unroll
    for (int s = 0; s < 2; ++s) {
        if (wm == s) {
#pragma unroll
            for (int mt = 0; mt < 4; ++mt)
#pragma unroll
                for (int r = 0; r < 4; ++r) {
                    int lrow = mt * 16 + (lane >> 4) * 4 + r;
#pragma unroll
                    for (int nt = 0; nt < 4; ++nt)
                        epi[lrow * 132 + wn * 64 + nt * 16 + (lane & 15)] = acc[mt][nt][r];
                }
        }
        __syncthreads();
        int gr0 = rowTile + s * 64;
#pragma unroll
        for (int k = 0; k < 8; ++k) {
            int f4 = tid + k * 256;     // 0..2047 float4 slots = 64 rows x 32
            int row = f4 >> 5, c4 = f4 & 31;
            if (gr0 + row < mc) {
                float4 v = *(const float4*)&epi[row * 132 + c4 * 4];
                *(float4*)&G[(long)(gr0 + row) * NTOT + n0 + c4 * 4] = v;
            }
        }
        __syncthreads();
    }
}

// ==== FUSED BMWx64-d GEMM+gates (no G matrix), BMW in {256,128} ==============
// Block owns rows [rowTile,+BMW) x d-cols [d0,+64) for ALL 5 gate strips.
// 8 waves: wm=w>>1 owns MF=BMW/64 m-frags (MF*16 rows); wd=w&1 (32-d slab).
// Per-wave acc: MF x 10 (5 gates x 2 subs).
// LDS/tile: A = [half:BMW/128][ks:2](128r x 64B) ; B = [g:5][ks:2](64r x 64B)
// = 40KB. dbuf. Row layout: byte = row*64 + ((chunk ^ ((row>>1)&3))<<4):
// frag ds_read_b128 = 2 lanes/bank-quad (free), stage global src = 4 rows x
// 64B contiguous per quarter-wave. Stage = NA+5 calls/tile (NA=BMW/64), linear
// LDS dest (tid*16B), inverse(=same XOR) swizzled global source.
// Pipeline per tile: barrier; STAGE(t+1 -> other buf); vmcnt(NA+5); barrier;
// compute (2 ks x 5 g clusters of 2*MF MFMA). Last tile: vmcnt(0).
#define SWZ2(r) (((r) >> 1) & 3)

template <int BMW>
__global__ __launch_bounds__(512, 2) void gemmF(const u16* __restrict__ A,
                                                const u16* __restrict__ BT,
                                                const float* __restrict__ bio,
                                                const float* __restrict__ bfl,
                                                const float* __restrict__ bfr,
                                                const void* __restrict__ c_in,
                                                void* __restrict__ c_out, int c_bf16,
                                                float* __restrict__ outF,
                                                u16* __restrict__ hnext,
                                                int lp, int level_off, int gm) {
    constexpr int MF    = BMW / 64;             // m-frags per wave (4 or 2)
    constexpr int NA    = BMW / 64;             // A stage calls (4 or 2)
    constexpr int ABASE = (BMW / 128) * 8192;   // u16: A bytes/2 (16384 or 8192)
    constexpr int BUFU  = ABASE + 20480;        // u16 per buffer (36864 or 28672)
    __shared__ __align__(16) u16 lds[2 * BUFU];
    const int tid  = threadIdx.x;
    const int lane = tid & 63;
    const int w    = tid >> 6;
    const int wm   = w >> 1;    // 0..3
    const int wd   = w & 1;     // 0..1

    // XCD-bijective swizzle; row-tile fastest within chunk (share B strips in L2)
    int nwg = gm * 16;
    int f = blockIdx.x;
    int q = nwg >> 3, r = nwg & 7;
    int xcd = f & 7, rank = f >> 3;
    int wg = (xcd < r ? xcd * (q + 1) : r * (q + 1) + (xcd - r) * q) + rank;
    int by = wg / gm;           // d-tile 0..15
    int bx = wg % gm;
    long rowTile = (long)bx * BMW;
    int d0 = by * 64;

    // ---- stage sources (per-thread). Dest is linear tid*16B per call. ----
    // A call c: half=c>>1, ks=c&1; region row = w*16 + (lane>>2).
    const u16* srcA[NA];
    {
        int rr_ = w * 16 + (lane >> 2);
        int ck_ = ((lane & 3) ^ SWZ2(rr_)) * 8;
#pragma unroll
        for (int c = 0; c < NA; ++c)
            srcA[c] = A + (rowTile + (c >> 1) * 128 + rr_) * (long)K2 + (c & 1) * 32 + ck_;
    }
    // B call g: strip g; ks = w&1; strip row = (w>>1)*16 + (lane>>2).
    const u16* srcB[5];
    {
        int sr_ = (w >> 1) * 16 + (lane >> 2);
        int ck_ = ((lane & 3) ^ SWZ2(sr_)) * 8;
#pragma unroll
        for (int g = 0; g < 5; ++g)
            srcB[g] = BT + (long)(g * 1024 + d0 + sr_) * K2 + (w & 1) * 32 + ck_;
    }

    // ---- fragment read offsets (u16), ks=0; A: +4096 per ks, B: +2048 ----
    const int qv = lane >> 4;
    int rA[MF];
#pragma unroll
    for (int mf = 0; mf < MF; ++mf) {
        int rg = wm * (MF * 16) + mf * 16 + (lane & 15);    // 0..BMW-1
        int half = rg >> 7, rl = rg & 127;
        rA[mf] = half * 8192 + rl * 32 + ((qv ^ SWZ2(rl)) * 8);
    }
    int rB[2];
#pragma unroll
    for (int sub = 0; sub < 2; ++sub) {
        int rb = wd * 32 + sub * 16 + (lane & 15);          // row in 64-row strip
        rB[sub] = rb * 32 + ((qv ^ SWZ2(rb)) * 8);
    }

    floatx4 acc[MF][10];
#pragma unroll
    for (int mf = 0; mf < MF; ++mf)
#pragma unroll
        for (int nf = 0; nf < 10; ++nf)
            acc[mf][nf] = (floatx4){0.f, 0.f, 0.f, 0.f};

#define GF_STAGE(TT, DD)                                                             \
    do {                                                                             \
        _Pragma("unroll")                                                            \
        for (int c = 0; c < NA; ++c)                                                 \
            __builtin_amdgcn_global_load_lds(                                        \
                (const __attribute__((address_space(1))) void*)(srcA[c] + (TT) * 64),\
                (__attribute__((address_space(3))) void*)(lds + (DD) * BUFU + (c >> 1) * 8192 + (c & 1) * 4096 + tid * 8), 16, 0, 0); \
        _Pragma("unroll")                                                            \
        for (int g = 0; g < 5; ++g)                                                  \
            __builtin_amdgcn_global_load_lds(                                        \
                (const __attribute__((address_space(1))) void*)(srcB[g] + (TT) * 64),\
                (__attribute__((address_space(3))) void*)(lds + (DD) * BUFU + ABASE + g * 4096 + (w & 1) * 2048 + (w >> 1) * 512 + lane * 8), 16, 0, 0); \
    } while (0)

    // prologue
    GF_STAGE(0, 0);

    for (int t = 0; t < 32; ++t) {
        int d = t & 1;
        asm volatile("s_barrier" ::: "memory");     // reads of buf d^1 done
        if (t < 31) {
            GF_STAGE(t + 1, d ^ 1);
            asm volatile("s_waitcnt vmcnt(%0)" :: "i"(NA + 5) : "memory"); // tile t landed
        } else {
            asm volatile("s_waitcnt vmcnt(0)" ::: "memory");
        }
        asm volatile("s_barrier" ::: "memory");     // all waves: tile t ready
        const u16* bufD = lds + d * BUFU;
#pragma unroll
        for (int ks = 0; ks < 2; ++ks) {
            short8 aF[MF];
#pragma unroll
            for (int mf = 0; mf < MF; ++mf)
                aF[mf] = *(const short8*)&bufD[rA[mf] + ks * 4096];
#pragma unroll
            for (int g = 0; g < 5; ++g) {
                short8 bF[2];
#pragma unroll
                for (int sub = 0; sub < 2; ++sub)
                    bF[sub] = *(const short8*)&bufD[ABASE + g * 4096 + ks * 2048 + rB[sub]];
                __builtin_amdgcn_s_setprio(1);
#pragma unroll
                for (int mf = 0; mf < MF; ++mf)
#pragma unroll
                    for (int sub = 0; sub < 2; ++sub)
                        acc[mf][g * 2 + sub] = __builtin_amdgcn_mfma_f32_16x16x32_bf16(
                            aF[mf], bF[sub], acc[mf][g * 2 + sub], 0, 0, 0);
                __builtin_amdgcn_s_setprio(0);
            }
        }
    }
#undef GF_STAGE

    // ---- fused epilogue: LSTM gate math straight from acc ----
    float bI[2], bO[2], bC[2], bL[2], bR[2];
    int dsub[2];
#pragma unroll
    for (int sub = 0; sub < 2; ++sub) {
        int dd = d0 + wd * 32 + sub * 16 + (lane & 15);
        dsub[sub] = dd;
        bI[sub] = bio[dd]; bO[sub] = bio[1024 + dd]; bC[sub] = bio[2048 + dd];
        bL[sub] = bfl[dd]; bR[sub] = bfr[dd];
    }
    int pmask = (1 << lp) - 1;
    int has_c = (c_in != nullptr);
#pragma unroll
    for (int mf = 0; mf < MF; ++mf) {
#pragma unroll
        for (int rr = 0; rr < 4; ++rr) {
            int row = wm * (MF * 16) + mf * 16 + (lane >> 4) * 4 + rr;
            long J = rowTile + row;
            int b = (int)(J >> lp), p = (int)(J & pmask);
            long ho = ((long)b * 255 + level_off + p) * H;
#pragma unroll
            for (int sub = 0; sub < 2; ++sub) {
                int dd = dsub[sub];
                float i_  = acc[mf][0 + sub][rr] + bI[sub];
                float o_  = acc[mf][2 + sub][rr] + bO[sub];
                float ck_ = acc[mf][4 + sub][rr] + bC[sub];
                float cv = sigf(i_) * tanh_(ck_);
                if (has_c) {
                    float fl_ = sigf(acc[mf][6 + sub][rr] + bL[sub]);
                    float fr_ = sigf(acc[mf][8 + sub][rr] + bR[sub]);
                    float cl, cr;
                    if (c_bf16) {
                        cl = bf2f(__builtin_nontemporal_load(
                                 (const u16*)c_in + (2 * J) * H + dd));
                        cr = bf2f(__builtin_nontemporal_load(
                                 (const u16*)c_in + (2 * J + 1) * H + dd));
                    } else {
                        cl = __builtin_nontemporal_load(
                                 (const float*)c_in + (2 * J) * H + dd);
                        cr = __builtin_nontemporal_load(
                                 (const float*)c_in + (2 * J + 1) * H + dd);
                    }
                    cv += fl_ * cl + fr_ * cr;
                }
                float hv = sigf(o_) * tanh_(cv);
                __builtin_nontemporal_store(hv, &outF[ho + dd]);
                if (c_bf16)
                    __builtin_nontemporal_store(f2bf(cv), (u16*)c_out + J * H + dd);
                else
                    __builtin_nontemporal_store(cv, (float*)c_out + J * H + dd);
                __builtin_nontemporal_store(f2bf(hv), hnext + J * H + dd);
            }
        }
    }
}

// ---- gates (float4): c = sig(i)tanh(ck)+sig(fl)cl+sig(fr)cr; h = sig(o)tanh(c) ----
__global__ void gates(const float* __restrict__ G, const float* __restrict__ bio,
                      const float* __restrict__ bfl, const float* __restrict__ bfr,
                      const void* __restrict__ c_in, void* __restrict__ c_out, int c_bf16,
                      float* __restrict__ outF, u16* __restrict__ hnext,
                      int lp, int level_off, int row0, int mc) {
    int idx = blockIdx.x * 256 + threadIdx.x;
    int j = idx >> 8;
    if (j >= mc) return;
    int d = (idx & 255) * 4;
    int J = row0 + j;
    int b = J >> lp, p = J & ((1 << lp) - 1);
    long gb = (long)j * NTOT;
    float4 gi = *(const float4*)&G[gb + d];
    float4 go = *(const float4*)&G[gb + 1024 + d];
    float4 gc = *(const float4*)&G[gb + 2048 + d];
    float4 gl = *(const float4*)&G[gb + 3072 + d];
    float4 gr = *(const float4*)&G[gb + 4096 + d];
    float4 bi = *(const float4*)&bio[d];
    float4 bo = *(const float4*)&bio[1024 + d];
    float4 bc = *(const float4*)&bio[2048 + d];
    float4 bl = *(const float4*)&bfl[d];
    float4 br = *(const float4*)&bfr[d];
    float clv[4] = {0.f, 0.f, 0.f, 0.f}, crv[4] = {0.f, 0.f, 0.f, 0.f};
    if (c_in) {
        long cb = ((long)b * (2 << lp) + 2 * p) * H + d;
        if (c_bf16) {
            uint2 ul = *(const uint2*)((const u16*)c_in + cb);
            uint2 ur = *(const uint2*)((const u16*)c_in + cb + H);
            clv[0] = bf2f((u16)ul.x); clv[1] = bf2f((u16)(ul.x >> 16));
            clv[2] = bf2f((u16)ul.y); clv[3] = bf2f((u16)(ul.y >> 16));
            crv[0] = bf2f((u16)ur.x); crv[1] = bf2f((u16)(ur.x >> 16));
            crv[2] = bf2f((u16)ur.y); crv[3] = bf2f((u16)(ur.y >> 16));
        } else {
            float4 l4 = *(const float4*)((const float*)c_in + cb);
            float4 r4 = *(const float4*)((const float*)c_in + cb + H);
            clv[0] = l4.x; clv[1] = l4.y; clv[2] = l4.z; clv[3] = l4.w;
            crv[0] = r4.x; crv[1] = r4.y; crv[2] = r4.z; crv[3] = r4.w;
        }
    }
    const float* fgi = (const float*)&gi; const float* fgo = (const float*)&go;
    const float* fgc = (const float*)&gc; const float* fgl = (const float*)&gl;
    const float* fgr = (const float*)&gr;
    const float* fbi = (const float*)&bi; const float* fbo = (const float*)&bo;
    const float* fbc = (const float*)&bc; const float* fbl = (const float*)&bl;
    const float* fbr = (const float*)&br;
    float cv[4], hv[4];
    int has_c = (c_in != nullptr);
#pragma unroll
    for (int qq = 0; qq < 4; ++qq) {
        float c = sigf(fgi[qq] + fbi[qq]) * tanh_(fgc[qq] + fbc[qq]);
        if (has_c)
            c += sigf(fgl[qq] + fbl[qq]) * clv[qq] + sigf(fgr[qq] + fbr[qq]) * crv[qq];
        cv[qq] = c;
        hv[qq] = sigf(fgo[qq] + fbo[qq]) * tanh_(c);
    }
    long co = (long)J * H + d;
    if (c_bf16) {
        uint2 oc; oc.x = pk2(cv[0], cv[1]); oc.y = pk2(cv[2], cv[3]);
        *(uint2*)((u16*)c_out + co) = oc;
    } else {
        *(float4*)((float*)c_out + co) = make_float4(cv[0], cv[1], cv[2], cv[3]);
    }
    long oi = ((long)b * 255 + level_off + p) * H + d;
    *(float4*)&outF[oi] = make_float4(hv[0], hv[1], hv[2], hv[3]);
    uint2 oh; oh.x = pk2(hv[0], hv[1]); oh.y = pk2(hv[2], hv[3]);
    *(uint2*)(hnext + (long)J * H + d) = oh;
}

__global__ void root_copy(const float* __restrict__ outF, const void* __restrict__ c_root,
                          int c_bf16, float* __restrict__ tail) {
    int idx = blockIdx.x * 256 + threadIdx.x;   // 131072
    if (idx < 65536) {
        int b = idx >> 10, d = idx & 1023;
        tail[idx] = outF[((long)b * 255 + 254) * H + d];
    } else {
        int i2 = idx - 65536;
        tail[idx] = c_bf16 ? bf2f(((const u16*)c_root)[i2]) : ((const float*)c_root)[i2];
    }
}

extern "C" void kernel_launch(void* const* d_in, const int* in_sizes, int n_in,
                              void* d_out, int out_size, void* d_ws, size_t ws_size,
                              hipStream_t stream) {
    const int* tokens = (const int*)d_in[0];
    const float* emb = (const float*)d_in[1];
    const float* Wio = (const float*)d_in[2];
    const float* bio = (const float*)d_in[3];
    const float* Uio = (const float*)d_in[4];
    const float* Wfl = (const float*)d_in[5];
    const float* bfl = (const float*)d_in[6];
    const float* Ufl = (const float*)d_in[7];
    const float* Wfr = (const float*)d_in[8];
    const float* bfr = (const float*)d_in[9];
    const float* Ufr = (const float*)d_in[10];
    float* outF = (float*)d_out;

    // ---- ws carve (adaptive) ----
    char* ws = (char*)d_ws;
    size_t off = 0;
    u16* WT   = (u16*)(ws + off); off += (size_t)NTOT * K2 * 2;        // 20.97 MB
    u16* leaf = (u16*)(ws + off); off += (size_t)BATCH * 256 * H * 2;  // 33.55 MB
    u16* hE   = (u16*)(ws + off); off += (size_t)8192 * H * 2;         // 16.78 MB
    u16* hO   = (u16*)(ws + off); off += (size_t)4096 * H * 2;         //  8.39 MB
    size_t cEf = (size_t)8192 * H, cOf = (size_t)4096 * H;             // elements
    int c_bf16 = (ws_size >= off + (cEf + cOf) * 4 + (size_t)512 * NTOT * 4) ? 0 : 1;
    size_t csz = c_bf16 ? 2 : 4;
    void* cE = (void*)(ws + off); off += cEf * csz;
    void* cO = (void*)(ws + off); off += cOf * csz;
    size_t avail = (ws_size > off) ? (ws_size - off) : 0;
    long Grows = (long)(avail / ((size_t)NTOT * 4));
    if (Grows > 512) Grows = 512;           // legacy path only handles m <= 512
    Grows &= ~127L;
    if (Grows < 128) Grows = 128;
    float* G = (float*)(ws + off);

    pack_weights<<<dim3(64, 160), 256, 0, stream>>>(Wio, Uio, Wfl, Ufl, Wfr, Ufr, WT);
    leaf_pack<<<16384, 256, 0, stream>>>(tokens, emb, leaf);

    const int off_out[8] = {0, 128, 192, 224, 240, 248, 252, 254};
    for (int li = 0; li < 8; ++li) {
        int lp = 7 - li;
        long m = (long)BATCH << lp;
        const u16* Acur = (li == 0) ? leaf : ((li & 1) ? hE : hO);
        u16* hnext = (li & 1) ? hO : hE;
        const void* c_in = (li == 0) ? nullptr : ((li & 1) ? cE : cO);
        void* c_out = (li & 1) ? cO : cE;
        if (m >= 4096) {
            int gm = (int)(m >> 8);
            gemmF<256><<<gm * 16, 512, 0, stream>>>(Acur, WT, bio, bfl, bfr,
                                                    c_in, c_out, c_bf16, outF, hnext,
                                                    lp, off_out[li], gm);
        } else if (m >= 1024) {
            int gm = (int)(m >> 7);
            gemmF<128><<<gm * 16, 512, 0, stream>>>(Acur, WT, bio, bfl, bfr,
                                                    c_in, c_out, c_bf16, outF, hnext,
                                                    lp, off_out[li], gm);
        } else {
            for (long row0 = 0; row0 < m; row0 += Grows) {
                int mc = (int)((m - row0 > Grows) ? Grows : (m - row0));
                dim3 grid((mc + BM - 1) / BM, NTOT / BN);
                gemm_bt<<<grid, 256, 0, stream>>>(Acur + row0 * K2, WT, G, mc);
                gates<<<mc, 256, 0, stream>>>(G, bio, bfl, bfr, c_in, c_out, c_bf16,
                                              outF, hnext, lp, off_out[li], (int)row0, mc);
            }
        }
    }
    root_copy<<<512, 256, 0, stream>>>(outF, cO, c_bf16, outF + (size_t)BATCH * 255 * H);
}

// Round 7
// 715.847 us; speedup vs baseline: 1.3978x; 1.2043x over previous
//
#include <hip/hip_runtime.h>
#include <stdint.h>

#define H     1024
#define K2    2048
#define NTOT  5120
#define BATCH 64
#define BM 128
#define BN 128
#define BK 64

typedef unsigned short u16;
typedef __attribute__((ext_vector_type(8))) short short8;
typedef __attribute__((ext_vector_type(4))) float floatx4;

__device__ __forceinline__ float bf2f(u16 u) {
    return __uint_as_float(((uint32_t)u) << 16);
}
__device__ __forceinline__ u16 f2bf(float f) {
    uint32_t u = __float_as_uint(f);
    u += 0x7fffu + ((u >> 16) & 1u);
    return (u16)(u >> 16);
}
__device__ __forceinline__ uint32_t pk2(float lo, float hi) {
    return (uint32_t)f2bf(lo) | ((uint32_t)f2bf(hi) << 16);
}
__device__ __forceinline__ float sigf(float x) {
    return 1.0f / (1.0f + __expf(-x));
}
__device__ __forceinline__ float tanh_(float x) {
    float e = __expf(-2.0f * fabsf(x));
    float r = (1.0f - e) / (1.0f + e);
    return copysignf(r, x);
}

// ---- pack weights (fp32 in) -> bf16 WT[n][k]; k<1024 from W, else U ----
__global__ void pack_weights(const float* __restrict__ Wio, const float* __restrict__ Uio,
                             const float* __restrict__ Wfl, const float* __restrict__ Ufl,
                             const float* __restrict__ Wfr, const float* __restrict__ Ufr,
                             u16* __restrict__ WT) {
    __shared__ u16 tile[32][33];
    int k0 = blockIdx.x * 32;
    int n0 = blockIdx.y * 32;
    const float *Wp, *Up; int ncols, nloc;
    if (n0 < 3072)      { Wp = Wio; Up = Uio; ncols = 3072; nloc = n0; }
    else if (n0 < 4096) { Wp = Wfl; Up = Ufl; ncols = 1024; nloc = n0 - 3072; }
    else                { Wp = Wfr; Up = Ufr; ncols = 1024; nloc = n0 - 4096; }
    int t = threadIdx.x;
    int c = t & 31, r = t >> 5;
#pragma unroll
    for (int i = 0; i < 4; ++i) {
        int rr = r + i * 8;
        int k = k0 + rr;
        float v = (k < 1024) ? Wp[(long)k * ncols + nloc + c]
                             : Up[(long)(k - 1024) * ncols + nloc + c];
        tile[rr][c] = f2bf(v);
    }
    __syncthreads();
#pragma unroll
    for (int i = 0; i < 4; ++i) {
        int rr = r + i * 8;
        WT[(long)(n0 + rr) * K2 + k0 + c] = tile[c][rr];
    }
}

// ---- leaf gather + fp32->bf16: leaf[node][d] = emb[tokens[node]][d] ----
__global__ void leaf_pack(const int* __restrict__ tokens, const float* __restrict__ emb,
                          u16* __restrict__ leaf) {
    int idx = blockIdx.x * 256 + threadIdx.x;   // 16384 blocks -> 4,194,304 float4
    int node = idx >> 8;
    int d4 = idx & 255;
    int tok = tokens[node];
    float4 v = ((const float4*)emb)[(long)tok * 256 + d4];
    uint2 o; o.x = pk2(v.x, v.y); o.y = pk2(v.z, v.w);
    ((uint2*)leaf)[(long)node * 256 + d4] = o;
}

// ---- GEMM (m97 structure, 128x128) legacy fallback ----
__global__ void gemm_bt(const u16* __restrict__ A, const u16* __restrict__ BT,
                        float* __restrict__ G, int mc) {
    __shared__ __align__(16) u16 AsBs[16896];   // 33,792 B; K-loop: As|Bs, epilogue: epi
    u16* As = AsBs;
    u16* Bs = AsBs + 8192;
    float* epi = (float*)AsBs;                  // 64 x 132 fp32
    int tid  = threadIdx.x;
    int lane = tid & 63;
    int w    = tid >> 6;
    int wm   = w >> 1, wn = w & 1;
    int rowTile = blockIdx.x * BM;
    int n0      = blockIdx.y * BN;

    const u16* asrc[4];
    const u16* bsrc[4];
#pragma unroll
    for (int cc = 0; cc < 4; ++cc) {
        int r = cc * 32 + w * 8 + (lane >> 3);
        int j = rowTile + r; if (j >= mc) j = mc - 1;
        asrc[cc] = A + (long)j * K2 + (lane & 7) * 8;
        bsrc[cc] = BT + (long)(n0 + r) * K2 + (lane & 7) * 8;
    }

    floatx4 acc[4][4];
#pragma unroll
    for (int mt = 0; mt < 4; ++mt)
#pragma unroll
        for (int nt = 0; nt < 4; ++nt)
            acc[mt][nt] = (floatx4){0.f, 0.f, 0.f, 0.f};

    for (int k0 = 0; k0 < K2; k0 += BK) {
#pragma unroll
        for (int cc = 0; cc < 4; ++cc) {
            __builtin_amdgcn_global_load_lds(
                (const __attribute__((address_space(1))) void*)(asrc[cc] + k0),
                (__attribute__((address_space(3))) void*)(As + cc * 2048 + w * 512), 16, 0, 0);
            __builtin_amdgcn_global_load_lds(
                (const __attribute__((address_space(1))) void*)(bsrc[cc] + k0),
                (__attribute__((address_space(3))) void*)(Bs + cc * 2048 + w * 512), 16, 0, 0);
        }
        __syncthreads();
#pragma unroll
        for (int kb = 0; kb < 2; ++kb) {
            int kfo = kb * 32 + (lane >> 4) * 8;
            short8 af[4], bfv[4];
#pragma unroll
            for (int mt = 0; mt < 4; ++mt)
                af[mt] = *(const short8*)&As[(wm * 64 + mt * 16 + (lane & 15)) * BK + kfo];
#pragma unroll
            for (int nt = 0; nt < 4; ++nt)
                bfv[nt] = *(const short8*)&Bs[(wn * 64 + nt * 16 + (lane & 15)) * BK + kfo];
#pragma unroll
            for (int mt = 0; mt < 4; ++mt)
#pragma unroll
                for (int nt = 0; nt < 4; ++nt)
                    acc[mt][nt] = __builtin_amdgcn_mfma_f32_16x16x32_bf16(
                        af[mt], bfv[nt], acc[mt][nt], 0, 0, 0);
        }
        __syncthreads();
    }

#pragma unroll
    for (int s = 0; s < 2; ++s) {
        if (wm == s) {
#pragma unroll
            for (int mt = 0; mt < 4; ++mt)
#pragma unroll
                for (int r = 0; r < 4; ++r) {
                    int lrow = mt * 16 + (lane >> 4) * 4 + r;
#pragma unroll
                    for (int nt = 0; nt < 4; ++nt)
                        epi[lrow * 132 + wn * 64 + nt * 16 + (lane & 15)] = acc[mt][nt][r];
                }
        }
        __syncthreads();
        int gr0 = rowTile + s * 64;
#pragma unroll
        for (int k = 0; k < 8; ++k) {
            int f4 = tid + k * 256;     // 0..2047 float4 slots = 64 rows x 32
            int row = f4 >> 5, c4 = f4 & 31;
            if (gr0 + row < mc) {
                float4 v = *(const float4*)&epi[row * 132 + c4 * 4];
                *(float4*)&G[(long)(gr0 + row) * NTOT + n0 + c4 * 4] = v;
            }
        }
        __syncthreads();
    }
}

// ==== FUSED BMWx64-d GEMM+gates (no G matrix), BMW in {256,128} ==============
// (unchanged from the passing round-6 kernel; see comments there)
#define SWZ2(r) (((r) >> 1) & 3)

template <int BMW>
__global__ __launch_bounds__(512, 2) void gemmF(const u16* __restrict__ A,
                                                const u16* __restrict__ BT,
                                                const float* __restrict__ bio,
                                                const float* __restrict__ bfl,
                                                const float* __restrict__ bfr,
                                                const void* __restrict__ c_in,
                                                void* __restrict__ c_out, int c_bf16,
                                                float* __restrict__ outF,
                                                u16* __restrict__ hnext,
                                                int lp, int level_off, int gm) {
    constexpr int MF    = BMW / 64;             // m-frags per wave (4 or 2)
    constexpr int NA    = BMW / 64;             // A stage calls (4 or 2)
    constexpr int ABASE = (BMW / 128) * 8192;   // u16: A bytes/2 (16384 or 8192)
    constexpr int BUFU  = ABASE + 20480;        // u16 per buffer (36864 or 28672)
    __shared__ __align__(16) u16 lds[2 * BUFU];
    const int tid  = threadIdx.x;
    const int lane = tid & 63;
    const int w    = tid >> 6;
    const int wm   = w >> 1;    // 0..3
    const int wd   = w & 1;     // 0..1

    int nwg = gm * 16;
    int f = blockIdx.x;
    int q = nwg >> 3, r = nwg & 7;
    int xcd = f & 7, rank = f >> 3;
    int wg = (xcd < r ? xcd * (q + 1) : r * (q + 1) + (xcd - r) * q) + rank;
    int by = wg / gm;           // d-tile 0..15
    int bx = wg % gm;
    long rowTile = (long)bx * BMW;
    int d0 = by * 64;

    const u16* srcA[NA];
    {
        int rr_ = w * 16 + (lane >> 2);
        int ck_ = ((lane & 3) ^ SWZ2(rr_)) * 8;
#pragma unroll
        for (int c = 0; c < NA; ++c)
            srcA[c] = A + (rowTile + (c >> 1) * 128 + rr_) * (long)K2 + (c & 1) * 32 + ck_;
    }
    const u16* srcB[5];
    {
        int sr_ = (w >> 1) * 16 + (lane >> 2);
        int ck_ = ((lane & 3) ^ SWZ2(sr_)) * 8;
#pragma unroll
        for (int g = 0; g < 5; ++g)
            srcB[g] = BT + (long)(g * 1024 + d0 + sr_) * K2 + (w & 1) * 32 + ck_;
    }

    const int qv = lane >> 4;
    int rA[MF];
#pragma unroll
    for (int mf = 0; mf < MF; ++mf) {
        int rg = wm * (MF * 16) + mf * 16 + (lane & 15);    // 0..BMW-1
        int half = rg >> 7, rl = rg & 127;
        rA[mf] = half * 8192 + rl * 32 + ((qv ^ SWZ2(rl)) * 8);
    }
    int rB[2];
#pragma unroll
    for (int sub = 0; sub < 2; ++sub) {
        int rb = wd * 32 + sub * 16 + (lane & 15);          // row in 64-row strip
        rB[sub] = rb * 32 + ((qv ^ SWZ2(rb)) * 8);
    }

    floatx4 acc[MF][10];
#pragma unroll
    for (int mf = 0; mf < MF; ++mf)
#pragma unroll
        for (int nf = 0; nf < 10; ++nf)
            acc[mf][nf] = (floatx4){0.f, 0.f, 0.f, 0.f};

#define GF_STAGE(TT, DD)                                                             \
    do {                                                                             \
        _Pragma("unroll")                                                            \
        for (int c = 0; c < NA; ++c)                                                 \
            __builtin_amdgcn_global_load_lds(                                        \
                (const __attribute__((address_space(1))) void*)(srcA[c] + (TT) * 64),\
                (__attribute__((address_space(3))) void*)(lds + (DD) * BUFU + (c >> 1) * 8192 + (c & 1) * 4096 + tid * 8), 16, 0, 0); \
        _Pragma("unroll")                                                            \
        for (int g = 0; g < 5; ++g)                                                  \
            __builtin_amdgcn_global_load_lds(                                        \
                (const __attribute__((address_space(1))) void*)(srcB[g] + (TT) * 64),\
                (__attribute__((address_space(3))) void*)(lds + (DD) * BUFU + ABASE + g * 4096 + (w & 1) * 2048 + (w >> 1) * 512 + lane * 8), 16, 0, 0); \
    } while (0)

    GF_STAGE(0, 0);

    for (int t = 0; t < 32; ++t) {
        int d = t & 1;
        asm volatile("s_barrier" ::: "memory");     // reads of buf d^1 done
        if (t < 31) {
            GF_STAGE(t + 1, d ^ 1);
            asm volatile("s_waitcnt vmcnt(%0)" :: "i"(NA + 5) : "memory"); // tile t landed
        } else {
            asm volatile("s_waitcnt vmcnt(0)" ::: "memory");
        }
        asm volatile("s_barrier" ::: "memory");     // all waves: tile t ready
        const u16* bufD = lds + d * BUFU;
#pragma unroll
        for (int ks = 0; ks < 2; ++ks) {
            short8 aF[MF];
#pragma unroll
            for (int mf = 0; mf < MF; ++mf)
                aF[mf] = *(const short8*)&bufD[rA[mf] + ks * 4096];
#pragma unroll
            for (int g = 0; g < 5; ++g) {
                short8 bF[2];
#pragma unroll
                for (int sub = 0; sub < 2; ++sub)
                    bF[sub] = *(const short8*)&bufD[ABASE + g * 4096 + ks * 2048 + rB[sub]];
                __builtin_amdgcn_s_setprio(1);
#pragma unroll
                for (int mf = 0; mf < MF; ++mf)
#pragma unroll
                    for (int sub = 0; sub < 2; ++sub)
                        acc[mf][g * 2 + sub] = __builtin_amdgcn_mfma_f32_16x16x32_bf16(
                            aF[mf], bF[sub], acc[mf][g * 2 + sub], 0, 0, 0);
                __builtin_amdgcn_s_setprio(0);
            }
        }
    }
#undef GF_STAGE

    // ---- fused epilogue: LSTM gate math straight from acc ----
    float bI[2], bO[2], bC[2], bL[2], bR[2];
    int dsub[2];
#pragma unroll
    for (int sub = 0; sub < 2; ++sub) {
        int dd = d0 + wd * 32 + sub * 16 + (lane & 15);
        dsub[sub] = dd;
        bI[sub] = bio[dd]; bO[sub] = bio[1024 + dd]; bC[sub] = bio[2048 + dd];
        bL[sub] = bfl[dd]; bR[sub] = bfr[dd];
    }
    int pmask = (1 << lp) - 1;
    int has_c = (c_in != nullptr);
#pragma unroll
    for (int mf = 0; mf < MF; ++mf) {
#pragma unroll
        for (int rr = 0; rr < 4; ++rr) {
            int row = wm * (MF * 16) + mf * 16 + (lane >> 4) * 4 + rr;
            long J = rowTile + row;
            int b = (int)(J >> lp), p = (int)(J & pmask);
            long ho = ((long)b * 255 + level_off + p) * H;
#pragma unroll
            for (int sub = 0; sub < 2; ++sub) {
                int dd = dsub[sub];
                float i_  = acc[mf][0 + sub][rr] + bI[sub];
                float o_  = acc[mf][2 + sub][rr] + bO[sub];
                float ck_ = acc[mf][4 + sub][rr] + bC[sub];
                float cv = sigf(i_) * tanh_(ck_);
                if (has_c) {
                    float fl_ = sigf(acc[mf][6 + sub][rr] + bL[sub]);
                    float fr_ = sigf(acc[mf][8 + sub][rr] + bR[sub]);
                    float cl, cr;
                    if (c_bf16) {
                        cl = bf2f(__builtin_nontemporal_load(
                                 (const u16*)c_in + (2 * J) * H + dd));
                        cr = bf2f(__builtin_nontemporal_load(
                                 (const u16*)c_in + (2 * J + 1) * H + dd));
                    } else {
                        cl = __builtin_nontemporal_load(
                                 (const float*)c_in + (2 * J) * H + dd);
                        cr = __builtin_nontemporal_load(
                                 (const float*)c_in + (2 * J + 1) * H + dd);
                    }
                    cv += fl_ * cl + fr_ * cr;
                }
                float hv = sigf(o_) * tanh_(cv);
                __builtin_nontemporal_store(hv, &outF[ho + dd]);
                if (c_bf16)
                    __builtin_nontemporal_store(f2bf(cv), (u16*)c_out + J * H + dd);
                else
                    __builtin_nontemporal_store(cv, (float*)c_out + J * H + dd);
                __builtin_nontemporal_store(f2bf(hv), hnext + J * H + dd);
            }
        }
    }
}

// ==== SPLIT-K fused partial GEMM for small levels (m <= 1024) ================
// Same body as gemmF<128> but: grid = RT x 16 x KS (exactly 256 blocks by
// construction), each block does K range [kOff, kOff + NT*64) and writes RAW
// partials (no bias/gates) to P[(ksx*mPad + J)*NTOT + g*1024 + dd].
// Rows >= mLim: reads clamp inside allocated A (harmless), stores guarded.
__global__ __launch_bounds__(512, 2) void gemmS(const u16* __restrict__ A,
                                                const u16* __restrict__ BT,
                                                float* __restrict__ P,
                                                int RT, int KS, int NT,
                                                int mLim, int mPad) {
    constexpr int ABASE = 8192;                 // u16
    constexpr int BUFU  = 28672;                // u16 per buffer (57,344 B)
    __shared__ __align__(16) u16 lds[2 * BUFU];
    const int tid  = threadIdx.x;
    const int lane = tid & 63;
    const int w    = tid >> 6;
    const int wm   = w >> 1;    // 0..3
    const int wd   = w & 1;     // 0..1

    int nwg = RT * 16 * KS;
    int f = blockIdx.x;
    int q = nwg >> 3, r = nwg & 7;
    int xcd = f & 7, rank = f >> 3;
    int wg = (xcd < r ? xcd * (q + 1) : r * (q + 1) + (xcd - r) * q) + rank;
    int bx  = wg % RT;
    int by  = (wg / RT) % 16;
    int ksx = wg / (RT * 16);
    long rowTile = (long)bx * 128;
    int d0 = by * 64;
    int kOff = ksx * (NT * 64);

    const u16* srcA[2];
    {
        int rr_ = w * 16 + (lane >> 2);
        int ck_ = ((lane & 3) ^ SWZ2(rr_)) * 8;
#pragma unroll
        for (int c = 0; c < 2; ++c)
            srcA[c] = A + (rowTile + rr_) * (long)K2 + kOff + c * 32 + ck_;
    }
    const u16* srcB[5];
    {
        int sr_ = (w >> 1) * 16 + (lane >> 2);
        int ck_ = ((lane & 3) ^ SWZ2(sr_)) * 8;
#pragma unroll
        for (int g = 0; g < 5; ++g)
            srcB[g] = BT + (long)(g * 1024 + d0 + sr_) * K2 + kOff + (w & 1) * 32 + ck_;
    }

    const int qv = lane >> 4;
    int rA[2];
#pragma unroll
    for (int mf = 0; mf < 2; ++mf) {
        int rl = wm * 32 + mf * 16 + (lane & 15);           // 0..127
        rA[mf] = rl * 32 + ((qv ^ SWZ2(rl)) * 8);
    }
    int rB[2];
#pragma unroll
    for (int sub = 0; sub < 2; ++sub) {
        int rb = wd * 32 + sub * 16 + (lane & 15);
        rB[sub] = rb * 32 + ((qv ^ SWZ2(rb)) * 8);
    }

    floatx4 acc[2][10];
#pragma unroll
    for (int mf = 0; mf < 2; ++mf)
#pragma unroll
        for (int nf = 0; nf < 10; ++nf)
            acc[mf][nf] = (floatx4){0.f, 0.f, 0.f, 0.f};

#define GS_STAGE(TT, DD)                                                             \
    do {                                                                             \
        _Pragma("unroll")                                                            \
        for (int c = 0; c < 2; ++c)                                                  \
            __builtin_amdgcn_global_load_lds(                                        \
                (const __attribute__((address_space(1))) void*)(srcA[c] + (TT) * 64),\
                (__attribute__((address_space(3))) void*)(lds + (DD) * BUFU + c * 4096 + tid * 8), 16, 0, 0); \
        _Pragma("unroll")                                                            \
        for (int g = 0; g < 5; ++g)                                                  \
            __builtin_amdgcn_global_load_lds(                                        \
                (const __attribute__((address_space(1))) void*)(srcB[g] + (TT) * 64),\
                (__attribute__((address_space(3))) void*)(lds + (DD) * BUFU + ABASE + g * 4096 + (w & 1) * 2048 + (w >> 1) * 512 + lane * 8), 16, 0, 0); \
    } while (0)

    GS_STAGE(0, 0);

    for (int t = 0; t < NT; ++t) {
        int d = t & 1;
        asm volatile("s_barrier" ::: "memory");
        if (t < NT - 1) {
            GS_STAGE(t + 1, d ^ 1);
            asm volatile("s_waitcnt vmcnt(7)" ::: "memory");
        } else {
            asm volatile("s_waitcnt vmcnt(0)" ::: "memory");
        }
        asm volatile("s_barrier" ::: "memory");
        const u16* bufD = lds + d * BUFU;
#pragma unroll
        for (int ks = 0; ks < 2; ++ks) {
            short8 aF[2];
#pragma unroll
            for (int mf = 0; mf < 2; ++mf)
                aF[mf] = *(const short8*)&bufD[rA[mf] + ks * 4096];
#pragma unroll
            for (int g = 0; g < 5; ++g) {
                short8 bF[2];
#pragma unroll
                for (int sub = 0; sub < 2; ++sub)
                    bF[sub] = *(const short8*)&bufD[ABASE + g * 4096 + ks * 2048 + rB[sub]];
                __builtin_amdgcn_s_setprio(1);
#pragma unroll
                for (int mf = 0; mf < 2; ++mf)
#pragma unroll
                    for (int sub = 0; sub < 2; ++sub)
                        acc[mf][g * 2 + sub] = __builtin_amdgcn_mfma_f32_16x16x32_bf16(
                            aF[mf], bF[sub], acc[mf][g * 2 + sub], 0, 0, 0);
                __builtin_amdgcn_s_setprio(0);
            }
        }
    }
#undef GS_STAGE

    // ---- epilogue: raw partial store ----
    int dsub[2];
#pragma unroll
    for (int sub = 0; sub < 2; ++sub)
        dsub[sub] = d0 + wd * 32 + sub * 16 + (lane & 15);
#pragma unroll
    for (int mf = 0; mf < 2; ++mf) {
#pragma unroll
        for (int rr = 0; rr < 4; ++rr) {
            int row = wm * 32 + mf * 16 + (lane >> 4) * 4 + rr;
            long J = rowTile + row;
            if (J < mLim) {
                long pb = ((long)ksx * mPad + J) * NTOT;
#pragma unroll
                for (int g = 0; g < 5; ++g)
#pragma unroll
                    for (int sub = 0; sub < 2; ++sub)
                        P[pb + g * 1024 + dsub[sub]] = acc[mf][g * 2 + sub][rr];
            }
        }
    }
}

// ---- reduce split-K partials + gate math ----
__global__ void redgate(const float* __restrict__ P, const float* __restrict__ bio,
                        const float* __restrict__ bfl, const float* __restrict__ bfr,
                        const void* __restrict__ c_in, void* __restrict__ c_out, int c_bf16,
                        float* __restrict__ outF, u16* __restrict__ hnext,
                        int lp, int level_off, int mc, int KS, int mPad) {
    int idx = blockIdx.x * 256 + threadIdx.x;
    int j = idx >> 8;
    if (j >= mc) return;
    int d = (idx & 255) * 4;
    int b = j >> lp, p = j & ((1 << lp) - 1);
    float ac[5][4] = {};
    for (int s = 0; s < KS; ++s) {
        long pb = ((long)s * mPad + j) * NTOT + d;
#pragma unroll
        for (int g = 0; g < 5; ++g) {
            float4 v = *(const float4*)&P[pb + g * 1024];
            ac[g][0] += v.x; ac[g][1] += v.y; ac[g][2] += v.z; ac[g][3] += v.w;
        }
    }
    float4 bi = *(const float4*)&bio[d];
    float4 bo = *(const float4*)&bio[1024 + d];
    float4 bc = *(const float4*)&bio[2048 + d];
    float4 bl = *(const float4*)&bfl[d];
    float4 br = *(const float4*)&bfr[d];
    const float* fbi = (const float*)&bi; const float* fbo = (const float*)&bo;
    const float* fbc = (const float*)&bc; const float* fbl = (const float*)&bl;
    const float* fbr = (const float*)&br;
    float clv[4], crv[4];
    {
        long cb = ((long)b * (2 << lp) + 2 * p) * H + d;
        if (c_bf16) {
            uint2 ul = *(const uint2*)((const u16*)c_in + cb);
            uint2 ur = *(const uint2*)((const u16*)c_in + cb + H);
            clv[0] = bf2f((u16)ul.x); clv[1] = bf2f((u16)(ul.x >> 16));
            clv[2] = bf2f((u16)ul.y); clv[3] = bf2f((u16)(ul.y >> 16));
            crv[0] = bf2f((u16)ur.x); crv[1] = bf2f((u16)(ur.x >> 16));
            crv[2] = bf2f((u16)ur.y); crv[3] = bf2f((u16)(ur.y >> 16));
        } else {
            float4 l4 = *(const float4*)((const float*)c_in + cb);
            float4 r4 = *(const float4*)((const float*)c_in + cb + H);
            clv[0] = l4.x; clv[1] = l4.y; clv[2] = l4.z; clv[3] = l4.w;
            crv[0] = r4.x; crv[1] = r4.y; crv[2] = r4.z; crv[3] = r4.w;
        }
    }
    float cv[4], hv[4];
#pragma unroll
    for (int qq = 0; qq < 4; ++qq) {
        float c = sigf(ac[0][qq] + fbi[qq]) * tanh_(ac[2][qq] + fbc[qq]);
        c += sigf(ac[3][qq] + fbl[qq]) * clv[qq] + sigf(ac[4][qq] + fbr[qq]) * crv[qq];
        cv[qq] = c;
        hv[qq] = sigf(ac[1][qq] + fbo[qq]) * tanh_(c);
    }
    long co = (long)j * H + d;
    if (c_bf16) {
        uint2 oc; oc.x = pk2(cv[0], cv[1]); oc.y = pk2(cv[2], cv[3]);
        *(uint2*)((u16*)c_out + co) = oc;
    } else {
        *(float4*)((float*)c_out + co) = make_float4(cv[0], cv[1], cv[2], cv[3]);
    }
    long oi = ((long)b * 255 + level_off + p) * H + d;
    *(float4*)&outF[oi] = make_float4(hv[0], hv[1], hv[2], hv[3]);
    uint2 oh; oh.x = pk2(hv[0], hv[1]); oh.y = pk2(hv[2], hv[3]);
    *(uint2*)(hnext + (long)j * H + d) = oh;
}

// ---- gates (legacy fallback path) ----
__global__ void gates(const float* __restrict__ G, const float* __restrict__ bio,
                      const float* __restrict__ bfl, const float* __restrict__ bfr,
                      const void* __restrict__ c_in, void* __restrict__ c_out, int c_bf16,
                      float* __restrict__ outF, u16* __restrict__ hnext,
                      int lp, int level_off, int row0, int mc) {
    int idx = blockIdx.x * 256 + threadIdx.x;
    int j = idx >> 8;
    if (j >= mc) return;
    int d = (idx & 255) * 4;
    int J = row0 + j;
    int b = J >> lp, p = J & ((1 << lp) - 1);
    long gb = (long)j * NTOT;
    float4 gi = *(const float4*)&G[gb + d];
    float4 go = *(const float4*)&G[gb + 1024 + d];
    float4 gc = *(const float4*)&G[gb + 2048 + d];
    float4 gl = *(const float4*)&G[gb + 3072 + d];
    float4 gr = *(const float4*)&G[gb + 4096 + d];
    float4 bi = *(const float4*)&bio[d];
    float4 bo = *(const float4*)&bio[1024 + d];
    float4 bc = *(const float4*)&bio[2048 + d];
    float4 bl = *(const float4*)&bfl[d];
    float4 br = *(const float4*)&bfr[d];
    float clv[4] = {0.f, 0.f, 0.f, 0.f}, crv[4] = {0.f, 0.f, 0.f, 0.f};
    if (c_in) {
        long cb = ((long)b * (2 << lp) + 2 * p) * H + d;
        if (c_bf16) {
            uint2 ul = *(const uint2*)((const u16*)c_in + cb);
            uint2 ur = *(const uint2*)((const u16*)c_in + cb + H);
            clv[0] = bf2f((u16)ul.x); clv[1] = bf2f((u16)(ul.x >> 16));
            clv[2] = bf2f((u16)ul.y); clv[3] = bf2f((u16)(ul.y >> 16));
            crv[0] = bf2f((u16)ur.x); crv[1] = bf2f((u16)(ur.x >> 16));
            crv[2] = bf2f((u16)ur.y); crv[3] = bf2f((u16)(ur.y >> 16));
        } else {
            float4 l4 = *(const float4*)((const float*)c_in + cb);
            float4 r4 = *(const float4*)((const float*)c_in + cb + H);
            clv[0] = l4.x; clv[1] = l4.y; clv[2] = l4.z; clv[3] = l4.w;
            crv[0] = r4.x; crv[1] = r4.y; crv[2] = r4.z; crv[3] = r4.w;
        }
    }
    const float* fgi = (const float*)&gi; const float* fgo = (const float*)&go;
    const float* fgc = (const float*)&gc; const float* fgl = (const float*)&gl;
    const float* fgr = (const float*)&gr;
    const float* fbi = (const float*)&bi; const float* fbo = (const float*)&bo;
    const float* fbc = (const float*)&bc; const float* fbl = (const float*)&bl;
    const float* fbr = (const float*)&br;
    float cv[4], hv[4];
    int has_c = (c_in != nullptr);
#pragma unroll
    for (int qq = 0; qq < 4; ++qq) {
        float c = sigf(fgi[qq] + fbi[qq]) * tanh_(fgc[qq] + fbc[qq]);
        if (has_c)
            c += sigf(fgl[qq] + fbl[qq]) * clv[qq] + sigf(fgr[qq] + fbr[qq]) * crv[qq];
        cv[qq] = c;
        hv[qq] = sigf(fgo[qq] + fbo[qq]) * tanh_(c);
    }
    long co = (long)J * H + d;
    if (c_bf16) {
        uint2 oc; oc.x = pk2(cv[0], cv[1]); oc.y = pk2(cv[2], cv[3]);
        *(uint2*)((u16*)c_out + co) = oc;
    } else {
        *(float4*)((float*)c_out + co) = make_float4(cv[0], cv[1], cv[2], cv[3]);
    }
    long oi = ((long)b * 255 + level_off + p) * H + d;
    *(float4*)&outF[oi] = make_float4(hv[0], hv[1], hv[2], hv[3]);
    uint2 oh; oh.x = pk2(hv[0], hv[1]); oh.y = pk2(hv[2], hv[3]);
    *(uint2*)(hnext + (long)J * H + d) = oh;
}

__global__ void root_copy(const float* __restrict__ outF, const void* __restrict__ c_root,
                          int c_bf16, float* __restrict__ tail) {
    int idx = blockIdx.x * 256 + threadIdx.x;   // 131072
    if (idx < 65536) {
        int b = idx >> 10, d = idx & 1023;
        tail[idx] = outF[((long)b * 255 + 254) * H + d];
    } else {
        int i2 = idx - 65536;
        tail[idx] = c_bf16 ? bf2f(((const u16*)c_root)[i2]) : ((const float*)c_root)[i2];
    }
}

extern "C" void kernel_launch(void* const* d_in, const int* in_sizes, int n_in,
                              void* d_out, int out_size, void* d_ws, size_t ws_size,
                              hipStream_t stream) {
    const int* tokens = (const int*)d_in[0];
    const float* emb = (const float*)d_in[1];
    const float* Wio = (const float*)d_in[2];
    const float* bio = (const float*)d_in[3];
    const float* Uio = (const float*)d_in[4];
    const float* Wfl = (const float*)d_in[5];
    const float* bfl = (const float*)d_in[6];
    const float* Ufl = (const float*)d_in[7];
    const float* Wfr = (const float*)d_in[8];
    const float* bfr = (const float*)d_in[9];
    const float* Ufr = (const float*)d_in[10];
    float* outF = (float*)d_out;

    // ---- ws carve (adaptive) ----
    char* ws = (char*)d_ws;
    size_t off = 0;
    u16* WT   = (u16*)(ws + off); off += (size_t)NTOT * K2 * 2;        // 20.97 MB
    u16* leaf = (u16*)(ws + off); off += (size_t)BATCH * 256 * H * 2;  // 33.55 MB
    u16* hE   = (u16*)(ws + off); off += (size_t)8192 * H * 2;         // 16.78 MB
    u16* hO   = (u16*)(ws + off); off += (size_t)4096 * H * 2;         //  8.39 MB
    size_t cEf = (size_t)8192 * H, cOf = (size_t)4096 * H;             // elements
    int c_bf16 = (ws_size >= off + (cEf + cOf) * 4 + (size_t)512 * NTOT * 4) ? 0 : 1;
    size_t csz = c_bf16 ? 2 : 4;
    void* cE = (void*)(ws + off); off += cEf * csz;
    void* cO = (void*)(ws + off); off += cOf * csz;
    size_t avail = (ws_size > off) ? (ws_size - off) : 0;
    // split-K partial buffer: 2048 rows x 5120 fp32 = 41.9 MB (overlaps legacy G)
    size_t Pbytes = (size_t)2048 * NTOT * 4;
    int splitOK = (avail >= Pbytes);
    float* P = (float*)(ws + off);
    long Grows = (long)(avail / ((size_t)NTOT * 4));
    if (Grows > 512) Grows = 512;           // legacy path only handles m <= 512
    Grows &= ~127L;
    if (Grows < 128) Grows = 128;
    float* G = (float*)(ws + off);

    pack_weights<<<dim3(64, 160), 256, 0, stream>>>(Wio, Uio, Wfl, Ufl, Wfr, Ufr, WT);
    leaf_pack<<<16384, 256, 0, stream>>>(tokens, emb, leaf);

    const int off_out[8] = {0, 128, 192, 224, 240, 248, 252, 254};
    for (int li = 0; li < 8; ++li) {
        int lp = 7 - li;
        long m = (long)BATCH << lp;
        const u16* Acur = (li == 0) ? leaf : ((li & 1) ? hE : hO);
        u16* hnext = (li & 1) ? hO : hE;
        const void* c_in = (li == 0) ? nullptr : ((li & 1) ? cE : cO);
        void* c_out = (li & 1) ? cO : cE;
        if (m >= 4096) {
            int gm = (int)(m >> 8);
            gemmF<256><<<gm * 16, 512, 0, stream>>>(Acur, WT, bio, bfl, bfr,
                                                    c_in, c_out, c_bf16, outF, hnext,
                                                    lp, off_out[li], gm);
        } else if (m >= 2048) {
            int gm = (int)(m >> 7);
            gemmF<128><<<gm * 16, 512, 0, stream>>>(Acur, WT, bio, bfl, bfr,
                                                    c_in, c_out, c_bf16, outF, hnext,
                                                    lp, off_out[li], gm);
        } else if (splitOK) {
            int KS = (m == 1024) ? 2 : (m == 512) ? 4 : (m == 256) ? 8 : 16;
            int RT = (m >= 128) ? (int)(m >> 7) : 1;
            int mPad = RT * 128;
            int NT = 32 / KS;
            gemmS<<<RT * 16 * KS, 512, 0, stream>>>(Acur, WT, P, RT, KS, NT,
                                                    (int)m, mPad);
            redgate<<<(int)m, 256, 0, stream>>>(P, bio, bfl, bfr, c_in, c_out, c_bf16,
                                                outF, hnext, lp, off_out[li],
                                                (int)m, KS, mPad);
        } else {
            for (long row0 = 0; row0 < m; row0 += Grows) {
                int mc = (int)((m - row0 > Grows) ? Grows : (m - row0));
                dim3 grid((mc + BM - 1) / BM, NTOT / BN);
                gemm_bt<<<grid, 256, 0, stream>>>(Acur + row0 * K2, WT, G, mc);
                gates<<<mc, 256, 0, stream>>>(G, bio, bfl, bfr, c_in, c_out, c_bf16,
                                              outF, hnext, lp, off_out[li], (int)row0, mc);
            }
        }
    }
    root_copy<<<512, 256, 0, stream>>>(outF, cO, c_bf16, outF + (size_t)BATCH * 255 * H);
}

// Round 8
// 705.959 us; speedup vs baseline: 1.4173x; 1.0140x over previous
//
#include <hip/hip_runtime.h>
#include <stdint.h>

#define H     1024
#define K2    2048
#define NTOT  5120
#define BATCH 64
#define BM 128
#define BN 128
#define BK 64

typedef unsigned short u16;
typedef __attribute__((ext_vector_type(8))) short short8;
typedef __attribute__((ext_vector_type(4))) float floatx4;

__device__ __forceinline__ float bf2f(u16 u) {
    return __uint_as_float(((uint32_t)u) << 16);
}
__device__ __forceinline__ u16 f2bf(float f) {
    uint32_t u = __float_as_uint(f);
    u += 0x7fffu + ((u >> 16) & 1u);
    return (u16)(u >> 16);
}
__device__ __forceinline__ uint32_t pk2(float lo, float hi) {
    return (uint32_t)f2bf(lo) | ((uint32_t)f2bf(hi) << 16);
}
__device__ __forceinline__ float sigf(float x) {
    return 1.0f / (1.0f + __expf(-x));
}
__device__ __forceinline__ float tanh_(float x) {
    float e = __expf(-2.0f * fabsf(x));
    float r = (1.0f - e) / (1.0f + e);
    return copysignf(r, x);
}

// ---- pack weights (fp32 in) -> bf16 WT[n][k]; k<1024 from W, else U ----
__global__ void pack_weights(const float* __restrict__ Wio, const float* __restrict__ Uio,
                             const float* __restrict__ Wfl, const float* __restrict__ Ufl,
                             const float* __restrict__ Wfr, const float* __restrict__ Ufr,
                             u16* __restrict__ WT) {
    __shared__ u16 tile[32][33];
    int k0 = blockIdx.x * 32;
    int n0 = blockIdx.y * 32;
    const float *Wp, *Up; int ncols, nloc;
    if (n0 < 3072)      { Wp = Wio; Up = Uio; ncols = 3072; nloc = n0; }
    else if (n0 < 4096) { Wp = Wfl; Up = Ufl; ncols = 1024; nloc = n0 - 3072; }
    else                { Wp = Wfr; Up = Ufr; ncols = 1024; nloc = n0 - 4096; }
    int t = threadIdx.x;
    int c = t & 31, r = t >> 5;
#pragma unroll
    for (int i = 0; i < 4; ++i) {
        int rr = r + i * 8;
        int k = k0 + rr;
        float v = (k < 1024) ? Wp[(long)k * ncols + nloc + c]
                             : Up[(long)(k - 1024) * ncols + nloc + c];
        tile[rr][c] = f2bf(v);
    }
    __syncthreads();
#pragma unroll
    for (int i = 0; i < 4; ++i) {
        int rr = r + i * 8;
        WT[(long)(n0 + rr) * K2 + k0 + c] = tile[c][rr];
    }
}

// ---- leaf gather + fp32->bf16: leaf[node][d] = emb[tokens[node]][d] ----
__global__ void leaf_pack(const int* __restrict__ tokens, const float* __restrict__ emb,
                          u16* __restrict__ leaf) {
    int idx = blockIdx.x * 256 + threadIdx.x;   // 16384 blocks -> 4,194,304 float4
    int node = idx >> 8;
    int d4 = idx & 255;
    int tok = tokens[node];
    float4 v = ((const float4*)emb)[(long)tok * 256 + d4];
    uint2 o; o.x = pk2(v.x, v.y); o.y = pk2(v.z, v.w);
    ((uint2*)leaf)[(long)node * 256 + d4] = o;
}

// ---- GEMM (m97 structure, 128x128) legacy fallback ----
__global__ void gemm_bt(const u16* __restrict__ A, const u16* __restrict__ BT,
                        float* __restrict__ G, int mc) {
    __shared__ __align__(16) u16 AsBs[16896];   // 33,792 B; K-loop: As|Bs, epilogue: epi
    u16* As = AsBs;
    u16* Bs = AsBs + 8192;
    float* epi = (float*)AsBs;                  // 64 x 132 fp32
    int tid  = threadIdx.x;
    int lane = tid & 63;
    int w    = tid >> 6;
    int wm   = w >> 1, wn = w & 1;
    int rowTile = blockIdx.x * BM;
    int n0      = blockIdx.y * BN;

    const u16* asrc[4];
    const u16* bsrc[4];
#pragma unroll
    for (int cc = 0; cc < 4; ++cc) {
        int r = cc * 32 + w * 8 + (lane >> 3);
        int j = rowTile + r; if (j >= mc) j = mc - 1;
        asrc[cc] = A + (long)j * K2 + (lane & 7) * 8;
        bsrc[cc] = BT + (long)(n0 + r) * K2 + (lane & 7) * 8;
    }

    floatx4 acc[4][4];
#pragma unroll
    for (int mt = 0; mt < 4; ++mt)
#pragma unroll
        for (int nt = 0; nt < 4; ++nt)
            acc[mt][nt] = (floatx4){0.f, 0.f, 0.f, 0.f};

    for (int k0 = 0; k0 < K2; k0 += BK) {
#pragma unroll
        for (int cc = 0; cc < 4; ++cc) {
            __builtin_amdgcn_global_load_lds(
                (const __attribute__((address_space(1))) void*)(asrc[cc] + k0),
                (__attribute__((address_space(3))) void*)(As + cc * 2048 + w * 512), 16, 0, 0);
            __builtin_amdgcn_global_load_lds(
                (const __attribute__((address_space(1))) void*)(bsrc[cc] + k0),
                (__attribute__((address_space(3))) void*)(Bs + cc * 2048 + w * 512), 16, 0, 0);
        }
        __syncthreads();
#pragma unroll
        for (int kb = 0; kb < 2; ++kb) {
            int kfo = kb * 32 + (lane >> 4) * 8;
            short8 af[4], bfv[4];
#pragma unroll
            for (int mt = 0; mt < 4; ++mt)
                af[mt] = *(const short8*)&As[(wm * 64 + mt * 16 + (lane & 15)) * BK + kfo];
#pragma unroll
            for (int nt = 0; nt < 4; ++nt)
                bfv[nt] = *(const short8*)&Bs[(wn * 64 + nt * 16 + (lane & 15)) * BK + kfo];
#pragma unroll
            for (int mt = 0; mt < 4; ++mt)
#pragma unroll
                for (int nt = 0; nt < 4; ++nt)
                    acc[mt][nt] = __builtin_amdgcn_mfma_f32_16x16x32_bf16(
                        af[mt], bfv[nt], acc[mt][nt], 0, 0, 0);
        }
        __syncthreads();
    }

#pragma unroll
    for (int s = 0; s < 2; ++s) {
        if (wm == s) {
#pragma unroll
            for (int mt = 0; mt < 4; ++mt)
#pragma unroll
                for (int r = 0; r < 4; ++r) {
                    int lrow = mt * 16 + (lane >> 4) * 4 + r;
#pragma unroll
                    for (int nt = 0; nt < 4; ++nt)
                        epi[lrow * 132 + wn * 64 + nt * 16 + (lane & 15)] = acc[mt][nt][r];
                }
        }
        __syncthreads();
        int gr0 = rowTile + s * 64;
#pragma unroll
        for (int k = 0; k < 8; ++k) {
            int f4 = tid + k * 256;     // 0..2047 float4 slots = 64 rows x 32
            int row = f4 >> 5, c4 = f4 & 31;
            if (gr0 + row < mc) {
                float4 v = *(const float4*)&epi[row * 132 + c4 * 4];
                *(float4*)&G[(long)(gr0 + row) * NTOT + n0 + c4 * 4] = v;
            }
        }
        __syncthreads();
    }
}

// ==== FUSED BMWx64-d GEMM+gates (no G matrix), BMW in {256,128} ==============
// (body identical to the passing round-7 kernel except the block->tile map)
#define SWZ2(r) (((r) >> 1) & 3)

template <int BMW>
__global__ __launch_bounds__(512, 2) void gemmF(const u16* __restrict__ A,
                                                const u16* __restrict__ BT,
                                                const float* __restrict__ bio,
                                                const float* __restrict__ bfl,
                                                const float* __restrict__ bfr,
                                                const void* __restrict__ c_in,
                                                void* __restrict__ c_out, int c_bf16,
                                                float* __restrict__ outF,
                                                u16* __restrict__ hnext,
                                                int lp, int level_off, int gm) {
    constexpr int MF    = BMW / 64;             // m-frags per wave (4 or 2)
    constexpr int NA    = BMW / 64;             // A stage calls (4 or 2)
    constexpr int ABASE = (BMW / 128) * 8192;   // u16: A bytes/2 (16384 or 8192)
    constexpr int BUFU  = ABASE + 20480;        // u16 per buffer (36864 or 28672)
    __shared__ __align__(16) u16 lds[2 * BUFU];
    const int tid  = threadIdx.x;
    const int lane = tid & 63;
    const int w    = tid >> 6;
    const int wm   = w >> 1;    // 0..3
    const int wd   = w & 1;     // 0..1

    // 2D XCD chunking (requires gm%4==0, true for all call sites): each XCD
    // owns 8 d-tiles x (gm/4) row-tiles, d-fastest within the chunk. The 32
    // resident blocks/XCD form a 4-row x 8-d rectangle -> per-k-tile working
    // set (4x32KB A + 8x80KB B slices) is L2-resident; each A panel is
    // fetched by exactly ONE XCD (kills the 8x A re-fetch of the old map).
    int f = blockIdx.x;
    int xcd = f & 7, c = f >> 3;
    int by = (xcd & 1) * 8 + (c & 7);            // d-tile 0..15
    int bx = (xcd >> 1) * (gm >> 2) + (c >> 3);  // row-tile 0..gm-1
    long rowTile = (long)bx * BMW;
    int d0 = by * 64;

    const u16* srcA[NA];
    {
        int rr_ = w * 16 + (lane >> 2);
        int ck_ = ((lane & 3) ^ SWZ2(rr_)) * 8;
#pragma unroll
        for (int cc = 0; cc < NA; ++cc)
            srcA[cc] = A + (rowTile + (cc >> 1) * 128 + rr_) * (long)K2 + (cc & 1) * 32 + ck_;
    }
    const u16* srcB[5];
    {
        int sr_ = (w >> 1) * 16 + (lane >> 2);
        int ck_ = ((lane & 3) ^ SWZ2(sr_)) * 8;
#pragma unroll
        for (int g = 0; g < 5; ++g)
            srcB[g] = BT + (long)(g * 1024 + d0 + sr_) * K2 + (w & 1) * 32 + ck_;
    }

    const int qv = lane >> 4;
    int rA[MF];
#pragma unroll
    for (int mf = 0; mf < MF; ++mf) {
        int rg = wm * (MF * 16) + mf * 16 + (lane & 15);    // 0..BMW-1
        int half = rg >> 7, rl = rg & 127;
        rA[mf] = half * 8192 + rl * 32 + ((qv ^ SWZ2(rl)) * 8);
    }
    int rB[2];
#pragma unroll
    for (int sub = 0; sub < 2; ++sub) {
        int rb = wd * 32 + sub * 16 + (lane & 15);          // row in 64-row strip
        rB[sub] = rb * 32 + ((qv ^ SWZ2(rb)) * 8);
    }

    floatx4 acc[MF][10];
#pragma unroll
    for (int mf = 0; mf < MF; ++mf)
#pragma unroll
        for (int nf = 0; nf < 10; ++nf)
            acc[mf][nf] = (floatx4){0.f, 0.f, 0.f, 0.f};

#define GF_STAGE(TT, DD)                                                             \
    do {                                                                             \
        _Pragma("unroll")                                                            \
        for (int cc = 0; cc < NA; ++cc)                                              \
            __builtin_amdgcn_global_load_lds(                                        \
                (const __attribute__((address_space(1))) void*)(srcA[cc] + (TT) * 64),\
                (__attribute__((address_space(3))) void*)(lds + (DD) * BUFU + (cc >> 1) * 8192 + (cc & 1) * 4096 + tid * 8), 16, 0, 0); \
        _Pragma("unroll")                                                            \
        for (int g = 0; g < 5; ++g)                                                  \
            __builtin_amdgcn_global_load_lds(                                        \
                (const __attribute__((address_space(1))) void*)(srcB[g] + (TT) * 64),\
                (__attribute__((address_space(3))) void*)(lds + (DD) * BUFU + ABASE + g * 4096 + (w & 1) * 2048 + (w >> 1) * 512 + lane * 8), 16, 0, 0); \
    } while (0)

    GF_STAGE(0, 0);

    for (int t = 0; t < 32; ++t) {
        int d = t & 1;
        asm volatile("s_barrier" ::: "memory");     // reads of buf d^1 done
        if (t < 31) {
            GF_STAGE(t + 1, d ^ 1);
            asm volatile("s_waitcnt vmcnt(%0)" :: "i"(NA + 5) : "memory"); // tile t landed
        } else {
            asm volatile("s_waitcnt vmcnt(0)" ::: "memory");
        }
        asm volatile("s_barrier" ::: "memory");     // all waves: tile t ready
        const u16* bufD = lds + d * BUFU;
#pragma unroll
        for (int ks = 0; ks < 2; ++ks) {
            short8 aF[MF];
#pragma unroll
            for (int mf = 0; mf < MF; ++mf)
                aF[mf] = *(const short8*)&bufD[rA[mf] + ks * 4096];
#pragma unroll
            for (int g = 0; g < 5; ++g) {
                short8 bF[2];
#pragma unroll
                for (int sub = 0; sub < 2; ++sub)
                    bF[sub] = *(const short8*)&bufD[ABASE + g * 4096 + ks * 2048 + rB[sub]];
                __builtin_amdgcn_s_setprio(1);
#pragma unroll
                for (int mf = 0; mf < MF; ++mf)
#pragma unroll
                    for (int sub = 0; sub < 2; ++sub)
                        acc[mf][g * 2 + sub] = __builtin_amdgcn_mfma_f32_16x16x32_bf16(
                            aF[mf], bF[sub], acc[mf][g * 2 + sub], 0, 0, 0);
                __builtin_amdgcn_s_setprio(0);
            }
        }
    }
#undef GF_STAGE

    // ---- fused epilogue: LSTM gate math straight from acc ----
    float bI[2], bO[2], bC[2], bL[2], bR[2];
    int dsub[2];
#pragma unroll
    for (int sub = 0; sub < 2; ++sub) {
        int dd = d0 + wd * 32 + sub * 16 + (lane & 15);
        dsub[sub] = dd;
        bI[sub] = bio[dd]; bO[sub] = bio[1024 + dd]; bC[sub] = bio[2048 + dd];
        bL[sub] = bfl[dd]; bR[sub] = bfr[dd];
    }
    int pmask = (1 << lp) - 1;
    int has_c = (c_in != nullptr);
#pragma unroll
    for (int mf = 0; mf < MF; ++mf) {
#pragma unroll
        for (int rr = 0; rr < 4; ++rr) {
            int row = wm * (MF * 16) + mf * 16 + (lane >> 4) * 4 + rr;
            long J = rowTile + row;
            int b = (int)(J >> lp), p = (int)(J & pmask);
            long ho = ((long)b * 255 + level_off + p) * H;
#pragma unroll
            for (int sub = 0; sub < 2; ++sub) {
                int dd = dsub[sub];
                float i_  = acc[mf][0 + sub][rr] + bI[sub];
                float o_  = acc[mf][2 + sub][rr] + bO[sub];
                float ck_ = acc[mf][4 + sub][rr] + bC[sub];
                float cv = sigf(i_) * tanh_(ck_);
                if (has_c) {
                    float fl_ = sigf(acc[mf][6 + sub][rr] + bL[sub]);
                    float fr_ = sigf(acc[mf][8 + sub][rr] + bR[sub]);
                    float cl, cr;
                    if (c_bf16) {
                        cl = bf2f(__builtin_nontemporal_load(
                                 (const u16*)c_in + (2 * J) * H + dd));
                        cr = bf2f(__builtin_nontemporal_load(
                                 (const u16*)c_in + (2 * J + 1) * H + dd));
                    } else {
                        cl = __builtin_nontemporal_load(
                                 (const float*)c_in + (2 * J) * H + dd);
                        cr = __builtin_nontemporal_load(
                                 (const float*)c_in + (2 * J + 1) * H + dd);
                    }
                    cv += fl_ * cl + fr_ * cr;
                }
                float hv = sigf(o_) * tanh_(cv);
                __builtin_nontemporal_store(hv, &outF[ho + dd]);
                if (c_bf16)
                    __builtin_nontemporal_store(f2bf(cv), (u16*)c_out + J * H + dd);
                else
                    __builtin_nontemporal_store(cv, (float*)c_out + J * H + dd);
                __builtin_nontemporal_store(f2bf(hv), hnext + J * H + dd);
            }
        }
    }
}

// ==== SPLIT-K fused partial GEMM for small levels (m <= 1024) ================
__global__ __launch_bounds__(512, 2) void gemmS(const u16* __restrict__ A,
                                                const u16* __restrict__ BT,
                                                float* __restrict__ P,
                                                int RT, int KS, int NT,
                                                int mLim, int mPad) {
    constexpr int ABASE = 8192;                 // u16
    constexpr int BUFU  = 28672;                // u16 per buffer (57,344 B)
    __shared__ __align__(16) u16 lds[2 * BUFU];
    const int tid  = threadIdx.x;
    const int lane = tid & 63;
    const int w    = tid >> 6;
    const int wm   = w >> 1;    // 0..3
    const int wd   = w & 1;     // 0..1

    int nwg = RT * 16 * KS;
    int f = blockIdx.x;
    int q = nwg >> 3, r = nwg & 7;
    int xcd = f & 7, rank = f >> 3;
    int wg = (xcd < r ? xcd * (q + 1) : r * (q + 1) + (xcd - r) * q) + rank;
    int bx  = wg % RT;
    int by  = (wg / RT) % 16;
    int ksx = wg / (RT * 16);
    long rowTile = (long)bx * 128;
    int d0 = by * 64;
    int kOff = ksx * (NT * 64);

    const u16* srcA[2];
    {
        int rr_ = w * 16 + (lane >> 2);
        int ck_ = ((lane & 3) ^ SWZ2(rr_)) * 8;
#pragma unroll
        for (int c = 0; c < 2; ++c)
            srcA[c] = A + (rowTile + rr_) * (long)K2 + kOff + c * 32 + ck_;
    }
    const u16* srcB[5];
    {
        int sr_ = (w >> 1) * 16 + (lane >> 2);
        int ck_ = ((lane & 3) ^ SWZ2(sr_)) * 8;
#pragma unroll
        for (int g = 0; g < 5; ++g)
            srcB[g] = BT + (long)(g * 1024 + d0 + sr_) * K2 + kOff + (w & 1) * 32 + ck_;
    }

    const int qv = lane >> 4;
    int rA[2];
#pragma unroll
    for (int mf = 0; mf < 2; ++mf) {
        int rl = wm * 32 + mf * 16 + (lane & 15);           // 0..127
        rA[mf] = rl * 32 + ((qv ^ SWZ2(rl)) * 8);
    }
    int rB[2];
#pragma unroll
    for (int sub = 0; sub < 2; ++sub) {
        int rb = wd * 32 + sub * 16 + (lane & 15);
        rB[sub] = rb * 32 + ((qv ^ SWZ2(rb)) * 8);
    }

    floatx4 acc[2][10];
#pragma unroll
    for (int mf = 0; mf < 2; ++mf)
#pragma unroll
        for (int nf = 0; nf < 10; ++nf)
            acc[mf][nf] = (floatx4){0.f, 0.f, 0.f, 0.f};

#define GS_STAGE(TT, DD)                                                             \
    do {                                                                             \
        _Pragma("unroll")                                                            \
        for (int c = 0; c < 2; ++c)                                                  \
            __builtin_amdgcn_global_load_lds(                                        \
                (const __attribute__((address_space(1))) void*)(srcA[c] + (TT) * 64),\
                (__attribute__((address_space(3))) void*)(lds + (DD) * BUFU + c * 4096 + tid * 8), 16, 0, 0); \
        _Pragma("unroll")                                                            \
        for (int g = 0; g < 5; ++g)                                                  \
            __builtin_amdgcn_global_load_lds(                                        \
                (const __attribute__((address_space(1))) void*)(srcB[g] + (TT) * 64),\
                (__attribute__((address_space(3))) void*)(lds + (DD) * BUFU + ABASE + g * 4096 + (w & 1) * 2048 + (w >> 1) * 512 + lane * 8), 16, 0, 0); \
    } while (0)

    GS_STAGE(0, 0);

    for (int t = 0; t < NT; ++t) {
        int d = t & 1;
        asm volatile("s_barrier" ::: "memory");
        if (t < NT - 1) {
            GS_STAGE(t + 1, d ^ 1);
            asm volatile("s_waitcnt vmcnt(7)" ::: "memory");
        } else {
            asm volatile("s_waitcnt vmcnt(0)" ::: "memory");
        }
        asm volatile("s_barrier" ::: "memory");
        const u16* bufD = lds + d * BUFU;
#pragma unroll
        for (int ks = 0; ks < 2; ++ks) {
            short8 aF[2];
#pragma unroll
            for (int mf = 0; mf < 2; ++mf)
                aF[mf] = *(const short8*)&bufD[rA[mf] + ks * 4096];
#pragma unroll
            for (int g = 0; g < 5; ++g) {
                short8 bF[2];
#pragma unroll
                for (int sub = 0; sub < 2; ++sub)
                    bF[sub] = *(const short8*)&bufD[ABASE + g * 4096 + ks * 2048 + rB[sub]];
                __builtin_amdgcn_s_setprio(1);
#pragma unroll
                for (int mf = 0; mf < 2; ++mf)
#pragma unroll
                    for (int sub = 0; sub < 2; ++sub)
                        acc[mf][g * 2 + sub] = __builtin_amdgcn_mfma_f32_16x16x32_bf16(
                            aF[mf], bF[sub], acc[mf][g * 2 + sub], 0, 0, 0);
                __builtin_amdgcn_s_setprio(0);
            }
        }
    }
#undef GS_STAGE

    int dsub[2];
#pragma unroll
    for (int sub = 0; sub < 2; ++sub)
        dsub[sub] = d0 + wd * 32 + sub * 16 + (lane & 15);
#pragma unroll
    for (int mf = 0; mf < 2; ++mf) {
#pragma unroll
        for (int rr = 0; rr < 4; ++rr) {
            int row = wm * 32 + mf * 16 + (lane >> 4) * 4 + rr;
            long J = rowTile + row;
            if (J < mLim) {
                long pb = ((long)ksx * mPad + J) * NTOT;
#pragma unroll
                for (int g = 0; g < 5; ++g)
#pragma unroll
                    for (int sub = 0; sub < 2; ++sub)
                        P[pb + g * 1024 + dsub[sub]] = acc[mf][g * 2 + sub][rr];
            }
        }
    }
}

// ---- reduce split-K partials + gate math ----
__global__ void redgate(const float* __restrict__ P, const float* __restrict__ bio,
                        const float* __restrict__ bfl, const float* __restrict__ bfr,
                        const void* __restrict__ c_in, void* __restrict__ c_out, int c_bf16,
                        float* __restrict__ outF, u16* __restrict__ hnext,
                        int lp, int level_off, int mc, int KS, int mPad) {
    int idx = blockIdx.x * 256 + threadIdx.x;
    int j = idx >> 8;
    if (j >= mc) return;
    int d = (idx & 255) * 4;
    int b = j >> lp, p = j & ((1 << lp) - 1);
    float ac[5][4] = {};
    for (int s = 0; s < KS; ++s) {
        long pb = ((long)s * mPad + j) * NTOT + d;
#pragma unroll
        for (int g = 0; g < 5; ++g) {
            float4 v = *(const float4*)&P[pb + g * 1024];
            ac[g][0] += v.x; ac[g][1] += v.y; ac[g][2] += v.z; ac[g][3] += v.w;
        }
    }
    float4 bi = *(const float4*)&bio[d];
    float4 bo = *(const float4*)&bio[1024 + d];
    float4 bc = *(const float4*)&bio[2048 + d];
    float4 bl = *(const float4*)&bfl[d];
    float4 br = *(const float4*)&bfr[d];
    const float* fbi = (const float*)&bi; const float* fbo = (const float*)&bo;
    const float* fbc = (const float*)&bc; const float* fbl = (const float*)&bl;
    const float* fbr = (const float*)&br;
    float clv[4], crv[4];
    {
        long cb = ((long)b * (2 << lp) + 2 * p) * H + d;
        if (c_bf16) {
            uint2 ul = *(const uint2*)((const u16*)c_in + cb);
            uint2 ur = *(const uint2*)((const u16*)c_in + cb + H);
            clv[0] = bf2f((u16)ul.x); clv[1] = bf2f((u16)(ul.x >> 16));
            clv[2] = bf2f((u16)ul.y); clv[3] = bf2f((u16)(ul.y >> 16));
            crv[0] = bf2f((u16)ur.x); crv[1] = bf2f((u16)(ur.x >> 16));
            crv[2] = bf2f((u16)ur.y); crv[3] = bf2f((u16)(ur.y >> 16));
        } else {
            float4 l4 = *(const float4*)((const float*)c_in + cb);
            float4 r4 = *(const float4*)((const float*)c_in + cb + H);
            clv[0] = l4.x; clv[1] = l4.y; clv[2] = l4.z; clv[3] = l4.w;
            crv[0] = r4.x; crv[1] = r4.y; crv[2] = r4.z; crv[3] = r4.w;
        }
    }
    float cv[4], hv[4];
#pragma unroll
    for (int qq = 0; qq < 4; ++qq) {
        float c = sigf(ac[0][qq] + fbi[qq]) * tanh_(ac[2][qq] + fbc[qq]);
        c += sigf(ac[3][qq] + fbl[qq]) * clv[qq] + sigf(ac[4][qq] + fbr[qq]) * crv[qq];
        cv[qq] = c;
        hv[qq] = sigf(ac[1][qq] + fbo[qq]) * tanh_(c);
    }
    long co = (long)j * H + d;
    if (c_bf16) {
        uint2 oc; oc.x = pk2(cv[0], cv[1]); oc.y = pk2(cv[2], cv[3]);
        *(uint2*)((u16*)c_out + co) = oc;
    } else {
        *(float4*)((float*)c_out + co) = make_float4(cv[0], cv[1], cv[2], cv[3]);
    }
    long oi = ((long)b * 255 + level_off + p) * H + d;
    *(float4*)&outF[oi] = make_float4(hv[0], hv[1], hv[2], hv[3]);
    uint2 oh; oh.x = pk2(hv[0], hv[1]); oh.y = pk2(hv[2], hv[3]);
    *(uint2*)(hnext + (long)j * H + d) = oh;
}

// ---- gates (legacy fallback path) ----
__global__ void gates(const float* __restrict__ G, const float* __restrict__ bio,
                      const float* __restrict__ bfl, const float* __restrict__ bfr,
                      const void* __restrict__ c_in, void* __restrict__ c_out, int c_bf16,
                      float* __restrict__ outF, u16* __restrict__ hnext,
                      int lp, int level_off, int row0, int mc) {
    int idx = blockIdx.x * 256 + threadIdx.x;
    int j = idx >> 8;
    if (j >= mc) return;
    int d = (idx & 255) * 4;
    int J = row0 + j;
    int b = J >> lp, p = J & ((1 << lp) - 1);
    long gb = (long)j * NTOT;
    float4 gi = *(const float4*)&G[gb + d];
    float4 go = *(const float4*)&G[gb + 1024 + d];
    float4 gc = *(const float4*)&G[gb + 2048 + d];
    float4 gl = *(const float4*)&G[gb + 3072 + d];
    float4 gr = *(const float4*)&G[gb + 4096 + d];
    float4 bi = *(const float4*)&bio[d];
    float4 bo = *(const float4*)&bio[1024 + d];
    float4 bc = *(const float4*)&bio[2048 + d];
    float4 bl = *(const float4*)&bfl[d];
    float4 br = *(const float4*)&bfr[d];
    float clv[4] = {0.f, 0.f, 0.f, 0.f}, crv[4] = {0.f, 0.f, 0.f, 0.f};
    if (c_in) {
        long cb = ((long)b * (2 << lp) + 2 * p) * H + d;
        if (c_bf16) {
            uint2 ul = *(const uint2*)((const u16*)c_in + cb);
            uint2 ur = *(const uint2*)((const u16*)c_in + cb + H);
            clv[0] = bf2f((u16)ul.x); clv[1] = bf2f((u16)(ul.x >> 16));
            clv[2] = bf2f((u16)ul.y); clv[3] = bf2f((u16)(ul.y >> 16));
            crv[0] = bf2f((u16)ur.x); crv[1] = bf2f((u16)(ur.x >> 16));
            crv[2] = bf2f((u16)ur.y); crv[3] = bf2f((u16)(ur.y >> 16));
        } else {
            float4 l4 = *(const float4*)((const float*)c_in + cb);
            float4 r4 = *(const float4*)((const float*)c_in + cb + H);
            clv[0] = l4.x; clv[1] = l4.y; clv[2] = l4.z; clv[3] = l4.w;
            crv[0] = r4.x; crv[1] = r4.y; crv[2] = r4.z; crv[3] = r4.w;
        }
    }
    const float* fgi = (const float*)&gi; const float* fgo = (const float*)&go;
    const float* fgc = (const float*)&gc; const float* fgl = (const float*)&gl;
    const float* fgr = (const float*)&gr;
    const float* fbi = (const float*)&bi; const float* fbo = (const float*)&bo;
    const float* fbc = (const float*)&bc; const float* fbl = (const float*)&bl;
    const float* fbr = (const float*)&br;
    float cv[4], hv[4];
    int has_c = (c_in != nullptr);
#pragma unroll
    for (int qq = 0; qq < 4; ++qq) {
        float c = sigf(fgi[qq] + fbi[qq]) * tanh_(fgc[qq] + fbc[qq]);
        if (has_c)
            c += sigf(fgl[qq] + fbl[qq]) * clv[qq] + sigf(fgr[qq] + fbr[qq]) * crv[qq];
        cv[qq] = c;
        hv[qq] = sigf(fgo[qq] + fbo[qq]) * tanh_(c);
    }
    long co = (long)J * H + d;
    if (c_bf16) {
        uint2 oc; oc.x = pk2(cv[0], cv[1]); oc.y = pk2(cv[2], cv[3]);
        *(uint2*)((u16*)c_out + co) = oc;
    } else {
        *(float4*)((float*)c_out + co) = make_float4(cv[0], cv[1], cv[2], cv[3]);
    }
    long oi = ((long)b * 255 + level_off + p) * H + d;
    *(float4*)&outF[oi] = make_float4(hv[0], hv[1], hv[2], hv[3]);
    uint2 oh; oh.x = pk2(hv[0], hv[1]); oh.y = pk2(hv[2], hv[3]);
    *(uint2*)(hnext + (long)J * H + d) = oh;
}

__global__ void root_copy(const float* __restrict__ outF, const void* __restrict__ c_root,
                          int c_bf16, float* __restrict__ tail) {
    int idx = blockIdx.x * 256 + threadIdx.x;   // 131072
    if (idx < 65536) {
        int b = idx >> 10, d = idx & 1023;
        tail[idx] = outF[((long)b * 255 + 254) * H + d];
    } else {
        int i2 = idx - 65536;
        tail[idx] = c_bf16 ? bf2f(((const u16*)c_root)[i2]) : ((const float*)c_root)[i2];
    }
}

extern "C" void kernel_launch(void* const* d_in, const int* in_sizes, int n_in,
                              void* d_out, int out_size, void* d_ws, size_t ws_size,
                              hipStream_t stream) {
    const int* tokens = (const int*)d_in[0];
    const float* emb = (const float*)d_in[1];
    const float* Wio = (const float*)d_in[2];
    const float* bio = (const float*)d_in[3];
    const float* Uio = (const float*)d_in[4];
    const float* Wfl = (const float*)d_in[5];
    const float* bfl = (const float*)d_in[6];
    const float* Ufl = (const float*)d_in[7];
    const float* Wfr = (const float*)d_in[8];
    const float* bfr = (const float*)d_in[9];
    const float* Ufr = (const float*)d_in[10];
    float* outF = (float*)d_out;

    // ---- ws carve (adaptive) ----
    char* ws = (char*)d_ws;
    size_t off = 0;
    u16* WT   = (u16*)(ws + off); off += (size_t)NTOT * K2 * 2;        // 20.97 MB
    u16* leaf = (u16*)(ws + off); off += (size_t)BATCH * 256 * H * 2;  // 33.55 MB
    u16* hE   = (u16*)(ws + off); off += (size_t)8192 * H * 2;         // 16.78 MB
    u16* hO   = (u16*)(ws + off); off += (size_t)4096 * H * 2;         //  8.39 MB
    size_t cEf = (size_t)8192 * H, cOf = (size_t)4096 * H;             // elements
    int c_bf16 = (ws_size >= off + (cEf + cOf) * 4 + (size_t)512 * NTOT * 4) ? 0 : 1;
    size_t csz = c_bf16 ? 2 : 4;
    void* cE = (void*)(ws + off); off += cEf * csz;
    void* cO = (void*)(ws + off); off += cOf * csz;
    size_t avail = (ws_size > off) ? (ws_size - off) : 0;
    // split-K partial buffer: 2048 rows x 5120 fp32 = 41.9 MB (overlaps legacy G)
    size_t Pbytes = (size_t)2048 * NTOT * 4;
    int splitOK = (avail >= Pbytes);
    float* P = (float*)(ws + off);
    long Grows = (long)(avail / ((size_t)NTOT * 4));
    if (Grows > 512) Grows = 512;           // legacy path only handles m <= 512
    Grows &= ~127L;
    if (Grows < 128) Grows = 128;
    float* G = (float*)(ws + off);

    pack_weights<<<dim3(64, 160), 256, 0, stream>>>(Wio, Uio, Wfl, Ufl, Wfr, Ufr, WT);
    leaf_pack<<<16384, 256, 0, stream>>>(tokens, emb, leaf);

    const int off_out[8] = {0, 128, 192, 224, 240, 248, 252, 254};
    for (int li = 0; li < 8; ++li) {
        int lp = 7 - li;
        long m = (long)BATCH << lp;
        const u16* Acur = (li == 0) ? leaf : ((li & 1) ? hE : hO);
        u16* hnext = (li & 1) ? hO : hE;
        const void* c_in = (li == 0) ? nullptr : ((li & 1) ? cE : cO);
        void* c_out = (li & 1) ? cO : cE;
        if (m >= 4096) {
            int gm = (int)(m >> 8);
            gemmF<256><<<gm * 16, 512, 0, stream>>>(Acur, WT, bio, bfl, bfr,
                                                    c_in, c_out, c_bf16, outF, hnext,
                                                    lp, off_out[li], gm);
        } else if (m >= 2048) {
            int gm = (int)(m >> 7);
            gemmF<128><<<gm * 16, 512, 0, stream>>>(Acur, WT, bio, bfl, bfr,
                                                    c_in, c_out, c_bf16, outF, hnext,
                                                    lp, off_out[li], gm);
        } else if (splitOK) {
            int KS = (m == 1024) ? 2 : (m == 512) ? 4 : (m == 256) ? 8 : 16;
            int RT = (m >= 128) ? (int)(m >> 7) : 1;
            int mPad = RT * 128;
            int NT = 32 / KS;
            gemmS<<<RT * 16 * KS, 512, 0, stream>>>(Acur, WT, P, RT, KS, NT,
                                                    (int)m, mPad);
            redgate<<<(int)m, 256, 0, stream>>>(P, bio, bfl, bfr, c_in, c_out, c_bf16,
                                                outF, hnext, lp, off_out[li],
                                                (int)m, KS, mPad);
        } else {
            for (long row0 = 0; row0 < m; row0 += Grows) {
                int mc = (int)((m - row0 > Grows) ? Grows : (m - row0));
                dim3 grid((mc + BM - 1) / BM, NTOT / BN);
                gemm_bt<<<grid, 256, 0, stream>>>(Acur + row0 * K2, WT, G, mc);
                gates<<<mc, 256, 0, stream>>>(G, bio, bfl, bfr, c_in, c_out, c_bf16,
                                              outF, hnext, lp, off_out[li], (int)row0, mc);
            }
        }
    }
    root_copy<<<512, 256, 0, stream>>>(outF, cO, c_bf16, outF + (size_t)BATCH * 255 * H);
}

// Round 9
// 661.289 us; speedup vs baseline: 1.5131x; 1.0675x over previous
//
#include <hip/hip_runtime.h>
#include <stdint.h>

#define H     1024
#define K2    2048
#define NTOT  5120
#define BATCH 64
#define BM 128
#define BN 128
#define BK 64

typedef unsigned short u16;
typedef __attribute__((ext_vector_type(8))) short short8;
typedef __attribute__((ext_vector_type(4))) float floatx4;

__device__ __forceinline__ float bf2f(u16 u) {
    return __uint_as_float(((uint32_t)u) << 16);
}
__device__ __forceinline__ u16 f2bf(float f) {
    uint32_t u = __float_as_uint(f);
    u += 0x7fffu + ((u >> 16) & 1u);
    return (u16)(u >> 16);
}
__device__ __forceinline__ uint32_t pk2(float lo, float hi) {
    return (uint32_t)f2bf(lo) | ((uint32_t)f2bf(hi) << 16);
}
__device__ __forceinline__ float sigf(float x) {
    return 1.0f / (1.0f + __expf(-x));
}
__device__ __forceinline__ float tanh_(float x) {
    float e = __expf(-2.0f * fabsf(x));
    float r = (1.0f - e) / (1.0f + e);
    return copysignf(r, x);
}

// ---- pack weights (fp32 in) -> bf16 WT[n][k]; k<1024 from W, else U ----
__global__ void pack_weights(const float* __restrict__ Wio, const float* __restrict__ Uio,
                             const float* __restrict__ Wfl, const float* __restrict__ Ufl,
                             const float* __restrict__ Wfr, const float* __restrict__ Ufr,
                             u16* __restrict__ WT) {
    __shared__ u16 tile[32][33];
    int k0 = blockIdx.x * 32;
    int n0 = blockIdx.y * 32;
    const float *Wp, *Up; int ncols, nloc;
    if (n0 < 3072)      { Wp = Wio; Up = Uio; ncols = 3072; nloc = n0; }
    else if (n0 < 4096) { Wp = Wfl; Up = Ufl; ncols = 1024; nloc = n0 - 3072; }
    else                { Wp = Wfr; Up = Ufr; ncols = 1024; nloc = n0 - 4096; }
    int t = threadIdx.x;
    int c = t & 31, r = t >> 5;
#pragma unroll
    for (int i = 0; i < 4; ++i) {
        int rr = r + i * 8;
        int k = k0 + rr;
        float v = (k < 1024) ? Wp[(long)k * ncols + nloc + c]
                             : Up[(long)(k - 1024) * ncols + nloc + c];
        tile[rr][c] = f2bf(v);
    }
    __syncthreads();
#pragma unroll
    for (int i = 0; i < 4; ++i) {
        int rr = r + i * 8;
        WT[(long)(n0 + rr) * K2 + k0 + c] = tile[c][rr];
    }
}

// ---- leaf gather + fp32->bf16: leaf[node][d] = emb[tokens[node]][d] ----
__global__ void leaf_pack(const int* __restrict__ tokens, const float* __restrict__ emb,
                          u16* __restrict__ leaf) {
    int idx = blockIdx.x * 256 + threadIdx.x;   // 16384 blocks -> 4,194,304 float4
    int node = idx >> 8;
    int d4 = idx & 255;
    int tok = tokens[node];
    float4 v = ((const float4*)emb)[(long)tok * 256 + d4];
    uint2 o; o.x = pk2(v.x, v.y); o.y = pk2(v.z, v.w);
    ((uint2*)leaf)[(long)node * 256 + d4] = o;
}

// ---- GEMM (m97 structure, 128x128) legacy fallback ----
__global__ void gemm_bt(const u16* __restrict__ A, const u16* __restrict__ BT,
                        float* __restrict__ G, int mc) {
    __shared__ __align__(16) u16 AsBs[16896];   // 33,792 B; K-loop: As|Bs, epilogue: epi
    u16* As = AsBs;
    u16* Bs = AsBs + 8192;
    float* epi = (float*)AsBs;                  // 64 x 132 fp32
    int tid  = threadIdx.x;
    int lane = tid & 63;
    int w    = tid >> 6;
    int wm   = w >> 1, wn = w & 1;
    int rowTile = blockIdx.x * BM;
    int n0      = blockIdx.y * BN;

    const u16* asrc[4];
    const u16* bsrc[4];
#pragma unroll
    for (int cc = 0; cc < 4; ++cc) {
        int r = cc * 32 + w * 8 + (lane >> 3);
        int j = rowTile + r; if (j >= mc) j = mc - 1;
        asrc[cc] = A + (long)j * K2 + (lane & 7) * 8;
        bsrc[cc] = BT + (long)(n0 + r) * K2 + (lane & 7) * 8;
    }

    floatx4 acc[4][4];
#pragma unroll
    for (int mt = 0; mt < 4; ++mt)
#pragma unroll
        for (int nt = 0; nt < 4; ++nt)
            acc[mt][nt] = (floatx4){0.f, 0.f, 0.f, 0.f};

    for (int k0 = 0; k0 < K2; k0 += BK) {
#pragma unroll
        for (int cc = 0; cc < 4; ++cc) {
            __builtin_amdgcn_global_load_lds(
                (const __attribute__((address_space(1))) void*)(asrc[cc] + k0),
                (__attribute__((address_space(3))) void*)(As + cc * 2048 + w * 512), 16, 0, 0);
            __builtin_amdgcn_global_load_lds(
                (const __attribute__((address_space(1))) void*)(bsrc[cc] + k0),
                (__attribute__((address_space(3))) void*)(Bs + cc * 2048 + w * 512), 16, 0, 0);
        }
        __syncthreads();
#pragma unroll
        for (int kb = 0; kb < 2; ++kb) {
            int kfo = kb * 32 + (lane >> 4) * 8;
            short8 af[4], bfv[4];
#pragma unroll
            for (int mt = 0; mt < 4; ++mt)
                af[mt] = *(const short8*)&As[(wm * 64 + mt * 16 + (lane & 15)) * BK + kfo];
#pragma unroll
            for (int nt = 0; nt < 4; ++nt)
                bfv[nt] = *(const short8*)&Bs[(wn * 64 + nt * 16 + (lane & 15)) * BK + kfo];
#pragma unroll
            for (int mt = 0; mt < 4; ++mt)
#pragma unroll
                for (int nt = 0; nt < 4; ++nt)
                    acc[mt][nt] = __builtin_amdgcn_mfma_f32_16x16x32_bf16(
                        af[mt], bfv[nt], acc[mt][nt], 0, 0, 0);
        }
        __syncthreads();
    }

#pragma unroll
    for (int s = 0; s < 2; ++s) {
        if (wm == s) {
#pragma unroll
            for (int mt = 0; mt < 4; ++mt)
#pragma unroll
                for (int r = 0; r < 4; ++r) {
                    int lrow = mt * 16 + (lane >> 4) * 4 + r;
#pragma unroll
                    for (int nt = 0; nt < 4; ++nt)
                        epi[lrow * 132 + wn * 64 + nt * 16 + (lane & 15)] = acc[mt][nt][r];
                }
        }
        __syncthreads();
        int gr0 = rowTile + s * 64;
#pragma unroll
        for (int k = 0; k < 8; ++k) {
            int f4 = tid + k * 256;     // 0..2047 float4 slots = 64 rows x 32
            int row = f4 >> 5, c4 = f4 & 31;
            if (gr0 + row < mc) {
                float4 v = *(const float4*)&epi[row * 132 + c4 * 4];
                *(float4*)&G[(long)(gr0 + row) * NTOT + n0 + c4 * 4] = v;
            }
        }
        __syncthreads();
    }
}

// ==== FUSED BMWx64-d GEMM+gates, 5-phase counted-vmcnt pipeline ==============
// Layout/staging/epilogue identical to round-8. K-loop restructured per T3/T4:
// one phase per gate g; per-wave FIFO (TOT=NA+5 loads/tile, consume order
// A x NA, B0..B4):
//   P0: vmcnt(4)      [drains A+B0]   read A(2ks x MF)+B0; stage A' (NA)
//   Pg (g=1..4): vmcnt(TOT-2) [drains Bg]  read Bg; stage B(g-1)'
//   after P4: stage B4'   -> TOT outstanding at tile end (steady state).
// Last tile: P0 vmcnt(4); Pg vmcnt(4-g) -> full drain only at t=31.
// Loads never drain to 0 in the main loop; 6-8 stay in flight across every
// barrier. One barrier per phase (RAW: all-waves vmcnt precedes barrier;
// WAR: double-buffered, prior-tile reads fenced by earlier barriers).
#define SWZ2(r) (((r) >> 1) & 3)

template <int BMW>
__global__ __launch_bounds__(512, 2) void gemmF(const u16* __restrict__ A,
                                                const u16* __restrict__ BT,
                                                const float* __restrict__ bio,
                                                const float* __restrict__ bfl,
                                                const float* __restrict__ bfr,
                                                const void* __restrict__ c_in,
                                                void* __restrict__ c_out, int c_bf16,
                                                float* __restrict__ outF,
                                                u16* __restrict__ hnext,
                                                int lp, int level_off, int gm) {
    constexpr int MF    = BMW / 64;             // m-frags per wave (4 or 2)
    constexpr int NA    = BMW / 64;             // A stage calls (4 or 2)
    constexpr int TOT   = NA + 5;               // stage calls per tile (9 or 7)
    constexpr int ABASE = (BMW / 128) * 8192;   // u16: A bytes/2 (16384 or 8192)
    constexpr int BUFU  = ABASE + 20480;        // u16 per buffer (36864 or 28672)
    __shared__ __align__(16) u16 lds[2 * BUFU];
    const int tid  = threadIdx.x;
    const int lane = tid & 63;
    const int w    = tid >> 6;
    const int wm   = w >> 1;    // 0..3
    const int wd   = w & 1;     // 0..1

    // 2D XCD chunking (gm%4==0 at all call sites): 8 d-tiles x gm/4 row-tiles
    // per XCD -> per-k-tile working set L2-resident; A fetched by ONE XCD.
    int f = blockIdx.x;
    int xcd = f & 7, c = f >> 3;
    int by = (xcd & 1) * 8 + (c & 7);            // d-tile 0..15
    int bx = (xcd >> 1) * (gm >> 2) + (c >> 3);  // row-tile 0..gm-1
    long rowTile = (long)bx * BMW;
    int d0 = by * 64;

    const u16* srcA[NA];
    {
        int rr_ = w * 16 + (lane >> 2);
        int ck_ = ((lane & 3) ^ SWZ2(rr_)) * 8;
#pragma unroll
        for (int cc = 0; cc < NA; ++cc)
            srcA[cc] = A + (rowTile + (cc >> 1) * 128 + rr_) * (long)K2 + (cc & 1) * 32 + ck_;
    }
    const u16* srcB[5];
    {
        int sr_ = (w >> 1) * 16 + (lane >> 2);
        int ck_ = ((lane & 3) ^ SWZ2(sr_)) * 8;
#pragma unroll
        for (int g = 0; g < 5; ++g)
            srcB[g] = BT + (long)(g * 1024 + d0 + sr_) * K2 + (w & 1) * 32 + ck_;
    }

    const int qv = lane >> 4;
    int rA[MF];
#pragma unroll
    for (int mf = 0; mf < MF; ++mf) {
        int rg = wm * (MF * 16) + mf * 16 + (lane & 15);    // 0..BMW-1
        int half = rg >> 7, rl = rg & 127;
        rA[mf] = half * 8192 + rl * 32 + ((qv ^ SWZ2(rl)) * 8);
    }
    int rB[2];
#pragma unroll
    for (int sub = 0; sub < 2; ++sub) {
        int rb = wd * 32 + sub * 16 + (lane & 15);          // row in 64-row strip
        rB[sub] = rb * 32 + ((qv ^ SWZ2(rb)) * 8);
    }

    floatx4 acc[MF][10];
#pragma unroll
    for (int mf = 0; mf < MF; ++mf)
#pragma unroll
        for (int nf = 0; nf < 10; ++nf)
            acc[mf][nf] = (floatx4){0.f, 0.f, 0.f, 0.f};

#define GF_STAGE_A(TT, DD)                                                           \
    do {                                                                             \
        _Pragma("unroll")                                                            \
        for (int cc = 0; cc < NA; ++cc)                                              \
            __builtin_amdgcn_global_load_lds(                                        \
                (const __attribute__((address_space(1))) void*)(srcA[cc] + (TT) * 64),\
                (__attribute__((address_space(3))) void*)(lds + (DD) * BUFU + (cc >> 1) * 8192 + (cc & 1) * 4096 + tid * 8), 16, 0, 0); \
    } while (0)

#define GF_STAGE_B(TT, DD, GG)                                                       \
    __builtin_amdgcn_global_load_lds(                                                \
        (const __attribute__((address_space(1))) void*)(srcB[GG] + (TT) * 64),       \
        (__attribute__((address_space(3))) void*)(lds + (DD) * BUFU + ABASE + (GG) * 4096 + (w & 1) * 2048 + (w >> 1) * 512 + lane * 8), 16, 0, 0)

#define GF_MFMA_G(GG)                                                                \
    do {                                                                             \
        __builtin_amdgcn_s_setprio(1);                                               \
        _Pragma("unroll")                                                            \
        for (int ks = 0; ks < 2; ++ks)                                               \
            _Pragma("unroll")                                                        \
            for (int mf = 0; mf < MF; ++mf)                                          \
                _Pragma("unroll")                                                    \
                for (int sub = 0; sub < 2; ++sub)                                    \
                    acc[mf][(GG) * 2 + sub] = __builtin_amdgcn_mfma_f32_16x16x32_bf16( \
                        aF[ks][mf], bF[ks][sub], acc[mf][(GG) * 2 + sub], 0, 0, 0);  \
        __builtin_amdgcn_s_setprio(0);                                               \
    } while (0)

    // prologue: stage tile 0 into buf 0 in consume order A, B0..B4
    GF_STAGE_A(0, 0);
#pragma unroll
    for (int g = 0; g < 5; ++g) GF_STAGE_B(0, 0, g);

    short8 aF[2][MF], bF[2][2];
    for (int t = 0; t < 32; ++t) {
        int d = t & 1;
        const u16* bufD = lds + d * BUFU;
        bool last = (t == 31);
        // ---- P0: A + gate 0 ----
        asm volatile("s_waitcnt vmcnt(%0)" :: "i"(TOT - NA - 1) : "memory");
        asm volatile("s_barrier" ::: "memory");
#pragma unroll
        for (int ks = 0; ks < 2; ++ks) {
#pragma unroll
            for (int mf = 0; mf < MF; ++mf)
                aF[ks][mf] = *(const short8*)&bufD[rA[mf] + ks * 4096];
#pragma unroll
            for (int sub = 0; sub < 2; ++sub)
                bF[ks][sub] = *(const short8*)&bufD[ABASE + ks * 2048 + rB[sub]];
        }
        if (!last) GF_STAGE_A(t + 1, d ^ 1);
        GF_MFMA_G(0);
        // ---- P1..P4: gate g ----
#pragma unroll
        for (int g = 1; g < 5; ++g) {
            if (!last) asm volatile("s_waitcnt vmcnt(%0)" :: "i"(TOT - 2) : "memory");
            else       asm volatile("s_waitcnt vmcnt(%0)" :: "i"(4 - g) : "memory");
            asm volatile("s_barrier" ::: "memory");
#pragma unroll
            for (int ks = 0; ks < 2; ++ks)
#pragma unroll
                for (int sub = 0; sub < 2; ++sub)
                    bF[ks][sub] = *(const short8*)&bufD[ABASE + g * 4096 + ks * 2048 + rB[sub]];
            if (!last) GF_STAGE_B(t + 1, d ^ 1, g - 1);
            GF_MFMA_G(g);
        }
        if (!last) GF_STAGE_B(t + 1, d ^ 1, 4);
    }
#undef GF_STAGE_A
#undef GF_STAGE_B
#undef GF_MFMA_G

    // ---- fused epilogue: LSTM gate math straight from acc ----
    float bI[2], bO[2], bC[2], bL[2], bR[2];
    int dsub[2];
#pragma unroll
    for (int sub = 0; sub < 2; ++sub) {
        int dd = d0 + wd * 32 + sub * 16 + (lane & 15);
        dsub[sub] = dd;
        bI[sub] = bio[dd]; bO[sub] = bio[1024 + dd]; bC[sub] = bio[2048 + dd];
        bL[sub] = bfl[dd]; bR[sub] = bfr[dd];
    }
    int pmask = (1 << lp) - 1;
    int has_c = (c_in != nullptr);
#pragma unroll
    for (int mf = 0; mf < MF; ++mf) {
#pragma unroll
        for (int rr = 0; rr < 4; ++rr) {
            int row = wm * (MF * 16) + mf * 16 + (lane >> 4) * 4 + rr;
            long J = rowTile + row;
            int b = (int)(J >> lp), p = (int)(J & pmask);
            long ho = ((long)b * 255 + level_off + p) * H;
#pragma unroll
            for (int sub = 0; sub < 2; ++sub) {
                int dd = dsub[sub];
                float i_  = acc[mf][0 + sub][rr] + bI[sub];
                float o_  = acc[mf][2 + sub][rr] + bO[sub];
                float ck_ = acc[mf][4 + sub][rr] + bC[sub];
                float cv = sigf(i_) * tanh_(ck_);
                if (has_c) {
                    float fl_ = sigf(acc[mf][6 + sub][rr] + bL[sub]);
                    float fr_ = sigf(acc[mf][8 + sub][rr] + bR[sub]);
                    float cl, cr;
                    if (c_bf16) {
                        cl = bf2f(__builtin_nontemporal_load(
                                 (const u16*)c_in + (2 * J) * H + dd));
                        cr = bf2f(__builtin_nontemporal_load(
                                 (const u16*)c_in + (2 * J + 1) * H + dd));
                    } else {
                        cl = __builtin_nontemporal_load(
                                 (const float*)c_in + (2 * J) * H + dd);
                        cr = __builtin_nontemporal_load(
                                 (const float*)c_in + (2 * J + 1) * H + dd);
                    }
                    cv += fl_ * cl + fr_ * cr;
                }
                float hv = sigf(o_) * tanh_(cv);
                __builtin_nontemporal_store(hv, &outF[ho + dd]);
                if (c_bf16)
                    __builtin_nontemporal_store(f2bf(cv), (u16*)c_out + J * H + dd);
                else
                    __builtin_nontemporal_store(cv, (float*)c_out + J * H + dd);
                __builtin_nontemporal_store(f2bf(hv), hnext + J * H + dd);
            }
        }
    }
}

// ==== SPLIT-K fused partial GEMM for small levels (m <= 1024) ================
__global__ __launch_bounds__(512, 2) void gemmS(const u16* __restrict__ A,
                                                const u16* __restrict__ BT,
                                                float* __restrict__ P,
                                                int RT, int KS, int NT,
                                                int mLim, int mPad) {
    constexpr int ABASE = 8192;                 // u16
    constexpr int BUFU  = 28672;                // u16 per buffer (57,344 B)
    __shared__ __align__(16) u16 lds[2 * BUFU];
    const int tid  = threadIdx.x;
    const int lane = tid & 63;
    const int w    = tid >> 6;
    const int wm   = w >> 1;    // 0..3
    const int wd   = w & 1;     // 0..1

    int nwg = RT * 16 * KS;
    int f = blockIdx.x;
    int q = nwg >> 3, r = nwg & 7;
    int xcd = f & 7, rank = f >> 3;
    int wg = (xcd < r ? xcd * (q + 1) : r * (q + 1) + (xcd - r) * q) + rank;
    int bx  = wg % RT;
    int by  = (wg / RT) % 16;
    int ksx = wg / (RT * 16);
    long rowTile = (long)bx * 128;
    int d0 = by * 64;
    int kOff = ksx * (NT * 64);

    const u16* srcA[2];
    {
        int rr_ = w * 16 + (lane >> 2);
        int ck_ = ((lane & 3) ^ SWZ2(rr_)) * 8;
#pragma unroll
        for (int c = 0; c < 2; ++c)
            srcA[c] = A + (rowTile + rr_) * (long)K2 + kOff + c * 32 + ck_;
    }
    const u16* srcB[5];
    {
        int sr_ = (w >> 1) * 16 + (lane >> 2);
        int ck_ = ((lane & 3) ^ SWZ2(sr_)) * 8;
#pragma unroll
        for (int g = 0; g < 5; ++g)
            srcB[g] = BT + (long)(g * 1024 + d0 + sr_) * K2 + kOff + (w & 1) * 32 + ck_;
    }

    const int qv = lane >> 4;
    int rA[2];
#pragma unroll
    for (int mf = 0; mf < 2; ++mf) {
        int rl = wm * 32 + mf * 16 + (lane & 15);           // 0..127
        rA[mf] = rl * 32 + ((qv ^ SWZ2(rl)) * 8);
    }
    int rB[2];
#pragma unroll
    for (int sub = 0; sub < 2; ++sub) {
        int rb = wd * 32 + sub * 16 + (lane & 15);
        rB[sub] = rb * 32 + ((qv ^ SWZ2(rb)) * 8);
    }

    floatx4 acc[2][10];
#pragma unroll
    for (int mf = 0; mf < 2; ++mf)
#pragma unroll
        for (int nf = 0; nf < 10; ++nf)
            acc[mf][nf] = (floatx4){0.f, 0.f, 0.f, 0.f};

#define GS_STAGE(TT, DD)                                                             \
    do {                                                                             \
        _Pragma("unroll")                                                            \
        for (int c = 0; c < 2; ++c)                                                  \
            __builtin_amdgcn_global_load_lds(                                        \
                (const __attribute__((address_space(1))) void*)(srcA[c] + (TT) * 64),\
                (__attribute__((address_space(3))) void*)(lds + (DD) * BUFU + c * 4096 + tid * 8), 16, 0, 0); \
        _Pragma("unroll")                                                            \
        for (int g = 0; g < 5; ++g)                                                  \
            __builtin_amdgcn_global_load_lds(                                        \
                (const __attribute__((address_space(1))) void*)(srcB[g] + (TT) * 64),\
                (__attribute__((address_space(3))) void*)(lds + (DD) * BUFU + ABASE + g * 4096 + (w & 1) * 2048 + (w >> 1) * 512 + lane * 8), 16, 0, 0); \
    } while (0)

    GS_STAGE(0, 0);

    for (int t = 0; t < NT; ++t) {
        int d = t & 1;
        asm volatile("s_barrier" ::: "memory");
        if (t < NT - 1) {
            GS_STAGE(t + 1, d ^ 1);
            asm volatile("s_waitcnt vmcnt(7)" ::: "memory");
        } else {
            asm volatile("s_waitcnt vmcnt(0)" ::: "memory");
        }
        asm volatile("s_barrier" ::: "memory");
        const u16* bufD = lds + d * BUFU;
#pragma unroll
        for (int ks = 0; ks < 2; ++ks) {
            short8 aF[2];
#pragma unroll
            for (int mf = 0; mf < 2; ++mf)
                aF[mf] = *(const short8*)&bufD[rA[mf] + ks * 4096];
#pragma unroll
            for (int g = 0; g < 5; ++g) {
                short8 bF[2];
#pragma unroll
                for (int sub = 0; sub < 2; ++sub)
                    bF[sub] = *(const short8*)&bufD[ABASE + g * 4096 + ks * 2048 + rB[sub]];
                __builtin_amdgcn_s_setprio(1);
#pragma unroll
                for (int mf = 0; mf < 2; ++mf)
#pragma unroll
                    for (int sub = 0; sub < 2; ++sub)
                        acc[mf][g * 2 + sub] = __builtin_amdgcn_mfma_f32_16x16x32_bf16(
                            aF[mf], bF[sub], acc[mf][g * 2 + sub], 0, 0, 0);
                __builtin_amdgcn_s_setprio(0);
            }
        }
    }
#undef GS_STAGE

    int dsub[2];
#pragma unroll
    for (int sub = 0; sub < 2; ++sub)
        dsub[sub] = d0 + wd * 32 + sub * 16 + (lane & 15);
#pragma unroll
    for (int mf = 0; mf < 2; ++mf) {
#pragma unroll
        for (int rr = 0; rr < 4; ++rr) {
            int row = wm * 32 + mf * 16 + (lane >> 4) * 4 + rr;
            long J = rowTile + row;
            if (J < mLim) {
                long pb = ((long)ksx * mPad + J) * NTOT;
#pragma unroll
                for (int g = 0; g < 5; ++g)
#pragma unroll
                    for (int sub = 0; sub < 2; ++sub)
                        P[pb + g * 1024 + dsub[sub]] = acc[mf][g * 2 + sub][rr];
            }
        }
    }
}

// ---- reduce split-K partials + gate math ----
__global__ void redgate(const float* __restrict__ P, const float* __restrict__ bio,
                        const float* __restrict__ bfl, const float* __restrict__ bfr,
                        const void* __restrict__ c_in, void* __restrict__ c_out, int c_bf16,
                        float* __restrict__ outF, u16* __restrict__ hnext,
                        int lp, int level_off, int mc, int KS, int mPad) {
    int idx = blockIdx.x * 256 + threadIdx.x;
    int j = idx >> 8;
    if (j >= mc) return;
    int d = (idx & 255) * 4;
    int b = j >> lp, p = j & ((1 << lp) - 1);
    float ac[5][4] = {};
    for (int s = 0; s < KS; ++s) {
        long pb = ((long)s * mPad + j) * NTOT + d;
#pragma unroll
        for (int g = 0; g < 5; ++g) {
            float4 v = *(const float4*)&P[pb + g * 1024];
            ac[g][0] += v.x; ac[g][1] += v.y; ac[g][2] += v.z; ac[g][3] += v.w;
        }
    }
    float4 bi = *(const float4*)&bio[d];
    float4 bo = *(const float4*)&bio[1024 + d];
    float4 bc = *(const float4*)&bio[2048 + d];
    float4 bl = *(const float4*)&bfl[d];
    float4 br = *(const float4*)&bfr[d];
    const float* fbi = (const float*)&bi; const float* fbo = (const float*)&bo;
    const float* fbc = (const float*)&bc; const float* fbl = (const float*)&bl;
    const float* fbr = (const float*)&br;
    float clv[4], crv[4];
    {
        long cb = ((long)b * (2 << lp) + 2 * p) * H + d;
        if (c_bf16) {
            uint2 ul = *(const uint2*)((const u16*)c_in + cb);
            uint2 ur = *(const uint2*)((const u16*)c_in + cb + H);
            clv[0] = bf2f((u16)ul.x); clv[1] = bf2f((u16)(ul.x >> 16));
            clv[2] = bf2f((u16)ul.y); clv[3] = bf2f((u16)(ul.y >> 16));
            crv[0] = bf2f((u16)ur.x); crv[1] = bf2f((u16)(ur.x >> 16));
            crv[2] = bf2f((u16)ur.y); crv[3] = bf2f((u16)(ur.y >> 16));
        } else {
            float4 l4 = *(const float4*)((const float*)c_in + cb);
            float4 r4 = *(const float4*)((const float*)c_in + cb + H);
            clv[0] = l4.x; clv[1] = l4.y; clv[2] = l4.z; clv[3] = l4.w;
            crv[0] = r4.x; crv[1] = r4.y; crv[2] = r4.z; crv[3] = r4.w;
        }
    }
    float cv[4], hv[4];
#pragma unroll
    for (int qq = 0; qq < 4; ++qq) {
        float c = sigf(ac[0][qq] + fbi[qq]) * tanh_(ac[2][qq] + fbc[qq]);
        c += sigf(ac[3][qq] + fbl[qq]) * clv[qq] + sigf(ac[4][qq] + fbr[qq]) * crv[qq];
        cv[qq] = c;
        hv[qq] = sigf(ac[1][qq] + fbo[qq]) * tanh_(c);
    }
    long co = (long)j * H + d;
    if (c_bf16) {
        uint2 oc; oc.x = pk2(cv[0], cv[1]); oc.y = pk2(cv[2], cv[3]);
        *(uint2*)((u16*)c_out + co) = oc;
    } else {
        *(float4*)((float*)c_out + co) = make_float4(cv[0], cv[1], cv[2], cv[3]);
    }
    long oi = ((long)b * 255 + level_off + p) * H + d;
    *(float4*)&outF[oi] = make_float4(hv[0], hv[1], hv[2], hv[3]);
    uint2 oh; oh.x = pk2(hv[0], hv[1]); oh.y = pk2(hv[2], hv[3]);
    *(uint2*)(hnext + (long)j * H + d) = oh;
}

// ---- gates (legacy fallback path) ----
__global__ void gates(const float* __restrict__ G, const float* __restrict__ bio,
                      const float* __restrict__ bfl, const float* __restrict__ bfr,
                      const void* __restrict__ c_in, void* __restrict__ c_out, int c_bf16,
                      float* __restrict__ outF, u16* __restrict__ hnext,
                      int lp, int level_off, int row0, int mc) {
    int idx = blockIdx.x * 256 + threadIdx.x;
    int j = idx >> 8;
    if (j >= mc) return;
    int d = (idx & 255) * 4;
    int J = row0 + j;
    int b = J >> lp, p = J & ((1 << lp) - 1);
    long gb = (long)j * NTOT;
    float4 gi = *(const float4*)&G[gb + d];
    float4 go = *(const float4*)&G[gb + 1024 + d];
    float4 gc = *(const float4*)&G[gb + 2048 + d];
    float4 gl = *(const float4*)&G[gb + 3072 + d];
    float4 gr = *(const float4*)&G[gb + 4096 + d];
    float4 bi = *(const float4*)&bio[d];
    float4 bo = *(const float4*)&bio[1024 + d];
    float4 bc = *(const float4*)&bio[2048 + d];
    float4 bl = *(const float4*)&bfl[d];
    float4 br = *(const float4*)&bfr[d];
    float clv[4] = {0.f, 0.f, 0.f, 0.f}, crv[4] = {0.f, 0.f, 0.f, 0.f};
    if (c_in) {
        long cb = ((long)b * (2 << lp) + 2 * p) * H + d;
        if (c_bf16) {
            uint2 ul = *(const uint2*)((const u16*)c_in + cb);
            uint2 ur = *(const uint2*)((const u16*)c_in + cb + H);
            clv[0] = bf2f((u16)ul.x); clv[1] = bf2f((u16)(ul.x >> 16));
            clv[2] = bf2f((u16)ul.y); clv[3] = bf2f((u16)(ul.y >> 16));
            crv[0] = bf2f((u16)ur.x); crv[1] = bf2f((u16)(ur.x >> 16));
            crv[2] = bf2f((u16)ur.y); crv[3] = bf2f((u16)(ur.y >> 16));
        } else {
            float4 l4 = *(const float4*)((const float*)c_in + cb);
            float4 r4 = *(const float4*)((const float*)c_in + cb + H);
            clv[0] = l4.x; clv[1] = l4.y; clv[2] = l4.z; clv[3] = l4.w;
            crv[0] = r4.x; crv[1] = r4.y; crv[2] = r4.z; crv[3] = r4.w;
        }
    }
    const float* fgi = (const float*)&gi; const float* fgo = (const float*)&go;
    const float* fgc = (const float*)&gc; const float* fgl = (const float*)&gl;
    const float* fgr = (const float*)&gr;
    const float* fbi = (const float*)&bi; const float* fbo = (const float*)&bo;
    const float* fbc = (const float*)&bc; const float* fbl = (const float*)&bl;
    const float* fbr = (const float*)&br;
    float cv[4], hv[4];
    int has_c = (c_in != nullptr);
#pragma unroll
    for (int qq = 0; qq < 4; ++qq) {
        float c = sigf(fgi[qq] + fbi[qq]) * tanh_(fgc[qq] + fbc[qq]);
        if (has_c)
            c += sigf(fgl[qq] + fbl[qq]) * clv[qq] + sigf(fgr[qq] + fbr[qq]) * crv[qq];
        cv[qq] = c;
        hv[qq] = sigf(fgo[qq] + fbo[qq]) * tanh_(c);
    }
    long co = (long)J * H + d;
    if (c_bf16) {
        uint2 oc; oc.x = pk2(cv[0], cv[1]); oc.y = pk2(cv[2], cv[3]);
        *(uint2*)((u16*)c_out + co) = oc;
    } else {
        *(float4*)((float*)c_out + co) = make_float4(cv[0], cv[1], cv[2], cv[3]);
    }
    long oi = ((long)b * 255 + level_off + p) * H + d;
    *(float4*)&outF[oi] = make_float4(hv[0], hv[1], hv[2], hv[3]);
    uint2 oh; oh.x = pk2(hv[0], hv[1]); oh.y = pk2(hv[2], hv[3]);
    *(uint2*)(hnext + (long)J * H + d) = oh;
}

__global__ void root_copy(const float* __restrict__ outF, const void* __restrict__ c_root,
                          int c_bf16, float* __restrict__ tail) {
    int idx = blockIdx.x * 256 + threadIdx.x;   // 131072
    if (idx < 65536) {
        int b = idx >> 10, d = idx & 1023;
        tail[idx] = outF[((long)b * 255 + 254) * H + d];
    } else {
        int i2 = idx - 65536;
        tail[idx] = c_bf16 ? bf2f(((const u16*)c_root)[i2]) : ((const float*)c_root)[i2];
    }
}

extern "C" void kernel_launch(void* const* d_in, const int* in_sizes, int n_in,
                              void* d_out, int out_size, void* d_ws, size_t ws_size,
                              hipStream_t stream) {
    const int* tokens = (const int*)d_in[0];
    const float* emb = (const float*)d_in[1];
    const float* Wio = (const float*)d_in[2];
    const float* bio = (const float*)d_in[3];
    const float* Uio = (const float*)d_in[4];
    const float* Wfl = (const float*)d_in[5];
    const float* bfl = (const float*)d_in[6];
    const float* Ufl = (const float*)d_in[7];
    const float* Wfr = (const float*)d_in[8];
    const float* bfr = (const float*)d_in[9];
    const float* Ufr = (const float*)d_in[10];
    float* outF = (float*)d_out;

    // ---- ws carve (adaptive) ----
    char* ws = (char*)d_ws;
    size_t off = 0;
    u16* WT   = (u16*)(ws + off); off += (size_t)NTOT * K2 * 2;        // 20.97 MB
    u16* leaf = (u16*)(ws + off); off += (size_t)BATCH * 256 * H * 2;  // 33.55 MB
    u16* hE   = (u16*)(ws + off); off += (size_t)8192 * H * 2;         // 16.78 MB
    u16* hO   = (u16*)(ws + off); off += (size_t)4096 * H * 2;         //  8.39 MB
    size_t cEf = (size_t)8192 * H, cOf = (size_t)4096 * H;             // elements
    int c_bf16 = (ws_size >= off + (cEf + cOf) * 4 + (size_t)512 * NTOT * 4) ? 0 : 1;
    size_t csz = c_bf16 ? 2 : 4;
    void* cE = (void*)(ws + off); off += cEf * csz;
    void* cO = (void*)(ws + off); off += cOf * csz;
    size_t avail = (ws_size > off) ? (ws_size - off) : 0;
    // split-K partial buffer: 2048 rows x 5120 fp32 = 41.9 MB (overlaps legacy G)
    size_t Pbytes = (size_t)2048 * NTOT * 4;
    int splitOK = (avail >= Pbytes);
    float* P = (float*)(ws + off);
    long Grows = (long)(avail / ((size_t)NTOT * 4));
    if (Grows > 512) Grows = 512;           // legacy path only handles m <= 512
    Grows &= ~127L;
    if (Grows < 128) Grows = 128;
    float* G = (float*)(ws + off);

    pack_weights<<<dim3(64, 160), 256, 0, stream>>>(Wio, Uio, Wfl, Ufl, Wfr, Ufr, WT);
    leaf_pack<<<16384, 256, 0, stream>>>(tokens, emb, leaf);

    const int off_out[8] = {0, 128, 192, 224, 240, 248, 252, 254};
    for (int li = 0; li < 8; ++li) {
        int lp = 7 - li;
        long m = (long)BATCH << lp;
        const u16* Acur = (li == 0) ? leaf : ((li & 1) ? hE : hO);
        u16* hnext = (li & 1) ? hO : hE;
        const void* c_in = (li == 0) ? nullptr : ((li & 1) ? cE : cO);
        void* c_out = (li & 1) ? cO : cE;
        if (m >= 4096) {
            int gm = (int)(m >> 8);
            gemmF<256><<<gm * 16, 512, 0, stream>>>(Acur, WT, bio, bfl, bfr,
                                                    c_in, c_out, c_bf16, outF, hnext,
                                                    lp, off_out[li], gm);
        } else if (m >= 2048) {
            int gm = (int)(m >> 7);
            gemmF<128><<<gm * 16, 512, 0, stream>>>(Acur, WT, bio, bfl, bfr,
                                                    c_in, c_out, c_bf16, outF, hnext,
                                                    lp, off_out[li], gm);
        } else if (splitOK) {
            int KS = (m == 1024) ? 2 : (m == 512) ? 4 : (m == 256) ? 8 : 16;
            int RT = (m >= 128) ? (int)(m >> 7) : 1;
            int mPad = RT * 128;
            int NT = 32 / KS;
            gemmS<<<RT * 16 * KS, 512, 0, stream>>>(Acur, WT, P, RT, KS, NT,
                                                    (int)m, mPad);
            redgate<<<(int)m, 256, 0, stream>>>(P, bio, bfl, bfr, c_in, c_out, c_bf16,
                                                outF, hnext, lp, off_out[li],
                                                (int)m, KS, mPad);
        } else {
            for (long row0 = 0; row0 < m; row0 += Grows) {
                int mc = (int)((m - row0 > Grows) ? Grows : (m - row0));
                dim3 grid((mc + BM - 1) / BM, NTOT / BN);
                gemm_bt<<<grid, 256, 0, stream>>>(Acur + row0 * K2, WT, G, mc);
                gates<<<mc, 256, 0, stream>>>(G, bio, bfl, bfr, c_in, c_out, c_bf16,
                                              outF, hnext, lp, off_out[li], (int)row0, mc);
            }
        }
    }
    root_copy<<<512, 256, 0, stream>>>(outF, cO, c_bf16, outF + (size_t)BATCH * 255 * H);
}